// Round 7
// baseline (554.261 us; speedup 1.0000x reference)
//
#include <hip/hip_runtime.h>
#include <cmath>

#define N_NODES 4096
#define FDIM    256
#define CDIM    40
#define NEDGE   131072
#define CAP     512                  // ELL row capacity (row nnz ~Poisson(64))
#define TWO_PI_F 6.28318530717958647692f

typedef __bf16 bf16;
typedef __bf16 bf16x2 __attribute__((ext_vector_type(2)));
typedef __bf16 bf16x4 __attribute__((ext_vector_type(4)));
typedef __bf16 bf16x8 __attribute__((ext_vector_type(8)));
typedef float  f32x4  __attribute__((ext_vector_type(4)));

static constexpr size_t NN = (size_t)N_NODES * N_NODES;   // 16,777,216
static constexpr size_t NF = (size_t)N_NODES * FDIM;      // 1,048,576

struct __align__(16) Entry { float lr, li; int col, pad; };

// async global->LDS, 16B per lane, dest = ldsBase + lane*16
__device__ __forceinline__ void gld_lds16(const bf16* g, bf16* s) {
    __builtin_amdgcn_global_load_lds(
        (const __attribute__((address_space(1))) void*)g,
        (__attribute__((address_space(3))) void*)s,
        16, 0, 0);
}

// ---------------------------------------------------------------------------
// 1. Scatter edges into dense A + accumulate raw row/col sums (all pre-zeroed)
// ---------------------------------------------------------------------------
__global__ void scatter_deg(const int* __restrict__ edges,
                            const float* __restrict__ w,
                            float* __restrict__ A,
                            float* __restrict__ rowsum,
                            float* __restrict__ colsum) {
    int e = blockIdx.x * blockDim.x + threadIdx.x;
    if (e < NEDGE) {
        int r = edges[e];
        int c = edges[NEDGE + e];
        float wv = w[e];
        atomicAdd(A + (size_t)r * N_NODES + c, wv);
        atomicAdd(rowsum + r, wv);
        atomicAdd(colsum + c, wv);
    }
}

// 2. dinv = (0.5*(rowsum+colsum))^-0.5 with 0 -> 1
__global__ void dinv_k(const float* __restrict__ rowsum,
                       const float* __restrict__ colsum,
                       float* __restrict__ dinv) {
    int j = blockIdx.x * blockDim.x + threadIdx.x;
    if (j < N_NODES) {
        float d = 0.5f * (rowsum[j] + colsum[j]);
        if (d == 0.f) d = 1.f;
        dinv[j] = 1.0f / sqrtf(d);
    }
}

// ---------------------------------------------------------------------------
// 3. ELL build: candidate cells = (r,c) and (c,r) per edge; bitmask dedup ->
//    colidx[i][pos], cnt[i]. mask/cnt/colidx pre-zeroed.
// ---------------------------------------------------------------------------
__global__ void build_cells(const int* __restrict__ edges,
                            unsigned* __restrict__ mask,
                            int* __restrict__ colidx,
                            int* __restrict__ cnt) {
    int e = blockIdx.x * blockDim.x + threadIdx.x;
    if (e >= 2 * NEDGE) return;
    int i, j;
    if (e < NEDGE) { i = edges[e];              j = edges[NEDGE + e]; }
    else           { int k = e - NEDGE; i = edges[NEDGE + k]; j = edges[k]; }
    int cell = i * N_NODES + j;
    unsigned bit = 1u << (cell & 31);
    unsigned old = atomicOr(mask + (cell >> 5), bit);
    if (!(old & bit)) {
        int pos = atomicAdd(cnt + i, 1);
        if (pos < CAP) colidx[(size_t)i * CAP + pos] = j;
    }
}

// ---------------------------------------------------------------------------
// 4. Fill ELL entries: L[i,j] = -a_n*exp(-i*Theta) from dense A.
//    ent is pre-zeroed, so every slot spmm could read is defined (zeros
//    contribute nothing even if counts were somehow inconsistent).
// ---------------------------------------------------------------------------
__global__ __launch_bounds__(256) void fill_ell(const int* __restrict__ colidx,
                                                const int* __restrict__ cnt,
                                                const float* __restrict__ A,
                                                const float* __restrict__ dinv,
                                                const float* __restrict__ qptr,
                                                Entry* __restrict__ ent) {
    int idx = blockIdx.x * 256 + threadIdx.x;     // 0 .. 4096*CAP-1
    int i = idx >> 9;                             // CAP = 512
    int p = idx & (CAP - 1);
    int n = cnt[i]; if (n > CAP) n = CAP;
    if (p >= n) return;
    int j = colidx[(size_t)i * CAP + p] & 4095;
    float a = A[(size_t)i * N_NODES + j];
    float b = A[(size_t)j * N_NODES + i];
    float an = 0.5f * (a + b) * dinv[i] * dinv[j];
    float s, c;
    sincosf(TWO_PI_F * qptr[0] * (a - b), &s, &c);
    Entry en; en.lr = -an * c; en.li = an * s; en.col = j; en.pad = 0;
    ent[(size_t)i * CAP + p] = en;
}

// ---------------------------------------------------------------------------
// 5. Cast X -> planar bf16 (wapply input) + interleaved bf16 (spmm input)
// ---------------------------------------------------------------------------
__global__ __launch_bounds__(256) void cast_in2(const float* __restrict__ Xr,
                                                const float* __restrict__ Xi,
                                                bf16* __restrict__ Xr16,
                                                bf16* __restrict__ Xi16,
                                                bf16* __restrict__ XC) {
    int idx = blockIdx.x * 256 + threadIdx.x;     // n*256+f
    float vr = Xr[idx], vi = Xi[idx];
    Xr16[idx] = (bf16)vr; Xi16[idx] = (bf16)vi;
    bf16x2 p; p[0] = (bf16)vr; p[1] = (bf16)vi;
    ((bf16x2*)XC)[idx] = p;
}

// cast W [3][256][256] -> Wt bf16 [256][768], Wt[n][o*256+k] = W[o][k][n]
__global__ __launch_bounds__(256) void cast_w(const float* __restrict__ W,
                                              bf16* __restrict__ Wt) {
    int idx = blockIdx.x * 256 + threadIdx.x;
    if (idx < 256 * 768) {
        int nout = idx / 768, kk = idx - nout * 768;
        int o = kk >> 8, k = kk & 255;
        Wt[idx] = (bf16)W[((size_t)o * 256 + k) * 256 + nout];
    }
}

// ---------------------------------------------------------------------------
// 6. Sparse complex SpMM (ELL): Z = alpha*(Lc @ Xc) + beta*C0.
//    One wave per row; XC interleaved [4096][256][2] bf16 (L2-resident, 4MB).
//    Entries fp32, fp32 accumulate. All reads statically bounded; ent zeroed.
// ---------------------------------------------------------------------------
__global__ __launch_bounds__(256) void spmm_k(
    const int* __restrict__ cnt, const Entry* __restrict__ ent,
    const bf16* __restrict__ XC,
    const float* __restrict__ C0r, const float* __restrict__ C0i,
    float alpha, float beta,
    bf16* __restrict__ Zr, bf16* __restrict__ Zi, bf16* __restrict__ ZC)
{
    int wave = threadIdx.x >> 6, lane = threadIdx.x & 63;
    int row = blockIdx.x * 4 + wave;
    int n1 = cnt[row]; if (n1 > CAP) n1 = CAP;
    const Entry* erow = ent + (size_t)row * CAP;

    float ar[4] = {}, ai[4] = {};
    if (n1 > 0) {
        Entry en = erow[0];
        for (int e = 0; e < n1; ++e) {
            Entry nxt = (e + 1 < n1) ? erow[e + 1] : en;   // prefetch
            int col = en.col & 4095;                        // defensive clamp
            bf16x8 x = *(const bf16x8*)&XC[(size_t)col * 512 + lane * 8];
            #pragma unroll
            for (int c = 0; c < 4; ++c) {
                float xr = (float)x[2 * c], xi = (float)x[2 * c + 1];
                ar[c] += en.lr * xr - en.li * xi;
                ai[c] += en.lr * xi + en.li * xr;
            }
            en = nxt;
        }
    }

    size_t base = (size_t)row * FDIM + lane * 4;
    float vr[4], vi[4];
    if (beta != 0.f) {
        f32x4 cr = *(const f32x4*)&C0r[base];
        f32x4 ci = *(const f32x4*)&C0i[base];
        #pragma unroll
        for (int c = 0; c < 4; ++c) {
            vr[c] = alpha * ar[c] + beta * cr[c];
            vi[c] = alpha * ai[c] + beta * ci[c];
        }
    } else {
        #pragma unroll
        for (int c = 0; c < 4; ++c) { vr[c] = alpha * ar[c]; vi[c] = alpha * ai[c]; }
    }
    bf16x4 pr, pi;
    #pragma unroll
    for (int c = 0; c < 4; ++c) { pr[c] = (bf16)vr[c]; pi[c] = (bf16)vi[c]; }
    *(bf16x4*)&Zr[base] = pr;
    *(bf16x4*)&Zi[base] = pi;
    if (ZC) {
        bf16x8 o;
        #pragma unroll
        for (int c = 0; c < 4; ++c) { o[2 * c] = pr[c]; o[2 * c + 1] = pi[c]; }
        *(bf16x8*)&ZC[(size_t)row * 512 + lane * 8] = o;
    }
}

// ---------------------------------------------------------------------------
// 7. wapply via MFMA: S = [Z0|Z1|Z2] @ Wcat (K=768); Or = b - Si; Oi = b + Sr
//    (R3-validated kernel, R3-validated argument patterns.)
// ---------------------------------------------------------------------------
__global__ __launch_bounds__(256) void wapply_mfma(
    const bf16* __restrict__ Z0r, const bf16* __restrict__ Z0i,
    const bf16* __restrict__ Z1r, const bf16* __restrict__ Z1i,
    const bf16* __restrict__ Z2r, const bf16* __restrict__ Z2i,
    const bf16* __restrict__ Wt,      // [256][768]
    const float* __restrict__ bias,   // [256]
    float* __restrict__ O32r, float* __restrict__ O32i,
    bf16* __restrict__ O16r_r, bf16* __restrict__ O16r_i,
    bf16* __restrict__ OC)
{
    __shared__ __align__(16) bf16 sZr[64 * 32];
    __shared__ __align__(16) bf16 sZi[64 * 32];
    __shared__ __align__(16) bf16 sW [64 * 32];

    const int tid  = threadIdx.x;
    const int wave = tid >> 6;
    const int lane = tid & 63;
    const int rowBase = blockIdx.y * 64;
    const int colBase = blockIdx.x * 64;

    const int srow = lane >> 2;
    const int skc  = (lane & 3) * 8;

    f32x4 accSr[2][2] = {}, accSi[2][2] = {};
    const int wm = wave & 1, wn = wave >> 1;
    const int fr = lane & 15;
    const int fk = (lane >> 4) * 8;

    for (int kb = 0; kb < 3 * FDIM; kb += 32) {
        int order = kb >> 8;
        int kloc  = kb & 255;
        if (wave == 0 || wave == 1) {
            const bf16* z;
            if (wave == 0) z = (order == 0) ? Z0r : (order == 1) ? Z1r : Z2r;
            else           z = (order == 0) ? Z0i : (order == 1) ? Z1i : Z2i;
            bf16* s = (wave == 0) ? sZr : sZi;
            const bf16* g = z + (size_t)(rowBase + srow) * FDIM + kloc + skc;
            #pragma unroll
            for (int t = 0; t < 4; ++t)
                gld_lds16(g + (size_t)t * 16 * FDIM, s + t * 512);
        } else if (wave == 2) {
            const bf16* g = Wt + (size_t)(colBase + srow) * 768 + kb + skc;
            #pragma unroll
            for (int t = 0; t < 4; ++t)
                gld_lds16(g + (size_t)t * 16 * 768, sW + t * 512);
        }
        __syncthreads();

        bf16x8 zr[2], zi[2], wv[2];
        #pragma unroll
        for (int m = 0; m < 2; ++m) {
            int r = wm * 32 + m * 16 + fr;
            zr[m] = *(const bf16x8*)&sZr[r * 32 + fk];
            zi[m] = *(const bf16x8*)&sZi[r * 32 + fk];
        }
        #pragma unroll
        for (int n = 0; n < 2; ++n) {
            int c = wn * 32 + n * 16 + fr;
            wv[n] = *(const bf16x8*)&sW[c * 32 + fk];
        }
        #pragma unroll
        for (int m = 0; m < 2; ++m)
            #pragma unroll
            for (int n = 0; n < 2; ++n) {
                accSr[m][n] = __builtin_amdgcn_mfma_f32_16x16x32_bf16(zr[m], wv[n], accSr[m][n], 0, 0, 0);
                accSi[m][n] = __builtin_amdgcn_mfma_f32_16x16x32_bf16(zi[m], wv[n], accSi[m][n], 0, 0, 0);
            }
        __syncthreads();
    }

    #pragma unroll
    for (int m = 0; m < 2; ++m)
        #pragma unroll
        for (int n = 0; n < 2; ++n) {
            int row0 = rowBase + wm * 32 + m * 16 + (lane >> 4) * 4;
            int col  = colBase + wn * 32 + n * 16 + (lane & 15);
            float bv = bias[col];
            #pragma unroll
            for (int r = 0; r < 4; ++r) {
                float vr = bv - accSi[m][n][r];
                float vi = bv + accSr[m][n][r];
                int row = row0 + r;
                size_t idx = (size_t)row * FDIM + col;
                if (O32r) {
                    O32r[idx] = vr; O32i[idx] = vi;
                }
                if (O16r_r) {
                    O16r_r[idx] = (bf16)vr; O16r_i[idx] = (bf16)vi;
                }
                if (OC) {
                    bf16x2 p; p[0] = (bf16)vr; p[1] = (bf16)vi;
                    ((bf16x2*)OC)[idx] = p;
                }
            }
        }
}

// ---------------------------------------------------------------------------
// 8. Head (R3-proven): logits = [r,i] @ Wc^T + bc; out = log_softmax.
//    One 64-thread wave per row.
// ---------------------------------------------------------------------------
__global__ __launch_bounds__(64) void head_k(
    const float* __restrict__ Yr, const float* __restrict__ Yi,
    const float* __restrict__ Wc,   // [40][512]
    const float* __restrict__ bc,   // [40]
    float* __restrict__ out)        // [N][40]
{
    int n = blockIdx.x;
    int t = threadIdx.x;
    __shared__ float x[2 * FDIM];
    for (int k = t; k < FDIM; k += 64) {
        x[k]        = Yr[(size_t)n * FDIM + k];
        x[FDIM + k] = Yi[(size_t)n * FDIM + k];
    }
    __syncthreads();

    float logit = -INFINITY;
    if (t < CDIM) {
        float s = bc[t];
        const float* w = Wc + (size_t)t * (2 * FDIM);
        #pragma unroll 8
        for (int k = 0; k < 2 * FDIM; ++k) s += x[k] * w[k];
        logit = s;
    }
    float m = logit;
    for (int off = 32; off; off >>= 1) m = fmaxf(m, __shfl_down(m, off));
    m = __shfl(m, 0);
    float e = (t < CDIM) ? expf(logit - m) : 0.f;
    float se = e;
    for (int off = 32; off; off >>= 1) se += __shfl_down(se, off);
    se = __shfl(se, 0);
    float lse = m + logf(se);
    if (t < CDIM) out[(size_t)n * CDIM + t] = logit - lse;
}

// ---------------------------------------------------------------------------
// Launcher
// ---------------------------------------------------------------------------
extern "C" void kernel_launch(void* const* d_in, const int* in_sizes, int n_in,
                              void* d_out, int out_size, void* d_ws, size_t ws_size,
                              hipStream_t stream) {
    const float* real = (const float*)d_in[0];
    const float* imag = (const float*)d_in[1];
    const int*   edges = (const int*)d_in[2];
    const float* q    = (const float*)d_in[3];
    const float* ew   = (const float*)d_in[4];
    const float* W1   = (const float*)d_in[5];
    const float* b1   = (const float*)d_in[6];
    const float* W2   = (const float*)d_in[7];
    const float* b2   = (const float*)d_in[8];
    const float* Wc   = (const float*)d_in[9];
    const float* bc   = (const float*)d_in[10];
    float* out = (float*)d_out;

    // ---- workspace carve-up ----
    // Zeroed region (single memset): A, mask, cnt, rowsum, colsum, colidx, ent.
    char* w = (char*)d_ws;
    float*    A      = (float*)w;    w += NN * 4;                        // 64 MB
    unsigned* mask   = (unsigned*)w; w += (NN / 32) * sizeof(unsigned);  // 2 MB
    int*      cnt    = (int*)w;      w += N_NODES * 4;
    float*    rowsum = (float*)w;    w += N_NODES * 4;
    float*    colsum = (float*)w;    w += N_NODES * 4;
    int*      colidx = (int*)w;      w += (size_t)N_NODES * CAP * 4;     // 8 MB
    Entry*    ent    = (Entry*)w;    w += (size_t)N_NODES * CAP * 16;    // 32 MB
    size_t zero_bytes = (size_t)((char*)w - (char*)d_ws);
    // Non-zeroed:
    float* dinv  = (float*)w; w += N_NODES * 4;
    bf16* Xr16 = (bf16*)w; w += NF * 2;
    bf16* Xi16 = (bf16*)w; w += NF * 2;
    bf16* XC   = (bf16*)w; w += NF * 4;                                  // interleaved
    bf16* Z1r  = (bf16*)w; w += NF * 2;
    bf16* Z1i  = (bf16*)w; w += NF * 2;
    bf16* Z1C  = (bf16*)w; w += NF * 4;
    bf16* Z2r  = (bf16*)w; w += NF * 2;
    bf16* Z2i  = (bf16*)w; w += NF * 2;
    float* Y1r32 = (float*)w; w += NF * 4;
    float* Y1i32 = (float*)w; w += NF * 4;
    bf16* Y1rb = (bf16*)w; w += NF * 2;
    bf16* Y1ib = (bf16*)w; w += NF * 2;
    bf16* Y1C  = (bf16*)w; w += NF * 4;
    float* Y2r32 = (float*)w; w += NF * 4;
    float* Y2i32 = (float*)w; w += NF * 4;
    bf16* W1t  = (bf16*)w; w += 256 * 768 * 2;
    bf16* W2t  = (bf16*)w; w += 256 * 768 * 2;

    hipMemsetAsync(d_ws, 0, zero_bytes, stream);

    // ---- build sparse L (ELL) ----
    scatter_deg<<<(NEDGE + 255) / 256, 256, 0, stream>>>(edges, ew, A, rowsum, colsum);
    dinv_k<<<16, 256, 0, stream>>>(rowsum, colsum, dinv);
    build_cells<<<(2 * NEDGE + 255) / 256, 256, 0, stream>>>(edges, mask, colidx, cnt);
    fill_ell<<<(N_NODES * CAP) / 256, 256, 0, stream>>>(colidx, cnt, A, dinv, q, ent);

    // ---- casts ----
    cast_in2<<<NF / 256, 256, 0, stream>>>(real, imag, Xr16, Xi16, XC);
    cast_w<<<768, 256, 0, stream>>>(W1, W1t);
    cast_w<<<768, 256, 0, stream>>>(W2, W2t);

    dim3 gW(FDIM / 64, N_NODES / 64);   // (4, 64)

    // ---- Layer 1 ----
    spmm_k<<<N_NODES / 4, 256, 0, stream>>>(cnt, ent, XC, nullptr, nullptr,
                                            1.f, 0.f, Z1r, Z1i, Z1C);
    spmm_k<<<N_NODES / 4, 256, 0, stream>>>(cnt, ent, Z1C, real, imag,
                                            2.f, -1.f, Z2r, Z2i, nullptr);
    wapply_mfma<<<gW, 256, 0, stream>>>(Xr16, Xi16, Z1r, Z1i, Z2r, Z2i,
                                        W1t, b1,
                                        Y1r32, Y1i32,
                                        Y1rb, Y1ib,
                                        Y1C);

    // ---- Layer 2 ----
    spmm_k<<<N_NODES / 4, 256, 0, stream>>>(cnt, ent, Y1C, nullptr, nullptr,
                                            1.f, 0.f, Z1r, Z1i, Z1C);
    spmm_k<<<N_NODES / 4, 256, 0, stream>>>(cnt, ent, Z1C, Y1r32, Y1i32,
                                            2.f, -1.f, Z2r, Z2i, nullptr);
    wapply_mfma<<<gW, 256, 0, stream>>>(Y1rb, Y1ib, Z1r, Z1i, Z2r, Z2i,
                                        W2t, b2,
                                        Y2r32, Y2i32,
                                        nullptr, nullptr,
                                        nullptr);

    // ---- Head (R3-proven) ----
    head_k<<<N_NODES, 64, 0, stream>>>(Y2r32, Y2i32, Wc, bc, out);
}

// Round 8
// 337.804 us; speedup vs baseline: 1.6408x; 1.6408x over previous
//
#include <hip/hip_runtime.h>
#include <cmath>

#define N_NODES 4096
#define FDIM    256
#define CDIM    40
#define NEDGE   131072
#define CAP     512                  // ELL row capacity (row nnz ~Poisson(64))
#define TWO_PI_F 6.28318530717958647692f

typedef __bf16 bf16;
typedef __bf16 bf16x2 __attribute__((ext_vector_type(2)));
typedef __bf16 bf16x4 __attribute__((ext_vector_type(4)));
typedef __bf16 bf16x8 __attribute__((ext_vector_type(8)));
typedef float  f32x4  __attribute__((ext_vector_type(4)));

static constexpr size_t NN = (size_t)N_NODES * N_NODES;   // 16,777,216
static constexpr size_t NF = (size_t)N_NODES * FDIM;      // 1,048,576

struct __align__(16) Entry { float lr, li; int col, pad; };

// async global->LDS, 16B per lane, dest = ldsBase + lane*16
__device__ __forceinline__ void gld_lds16(const bf16* g, bf16* s) {
    __builtin_amdgcn_global_load_lds(
        (const __attribute__((address_space(1))) void*)g,
        (__attribute__((address_space(3))) void*)s,
        16, 0, 0);
}

// ---------------------------------------------------------------------------
// 1. Scatter edges into dense A + accumulate raw row/col sums (all pre-zeroed)
// ---------------------------------------------------------------------------
__global__ void scatter_deg(const int* __restrict__ edges,
                            const float* __restrict__ w,
                            float* __restrict__ A,
                            float* __restrict__ rowsum,
                            float* __restrict__ colsum) {
    int e = blockIdx.x * blockDim.x + threadIdx.x;
    if (e < NEDGE) {
        int r = edges[e];
        int c = edges[NEDGE + e];
        float wv = w[e];
        atomicAdd(A + (size_t)r * N_NODES + c, wv);
        atomicAdd(rowsum + r, wv);
        atomicAdd(colsum + c, wv);
    }
}

// 2. dinv = (0.5*(rowsum+colsum))^-0.5 with 0 -> 1
__global__ void dinv_k(const float* __restrict__ rowsum,
                       const float* __restrict__ colsum,
                       float* __restrict__ dinv) {
    int j = blockIdx.x * blockDim.x + threadIdx.x;
    if (j < N_NODES) {
        float d = 0.5f * (rowsum[j] + colsum[j]);
        if (d == 0.f) d = 1.f;
        dinv[j] = 1.0f / sqrtf(d);
    }
}

// ---------------------------------------------------------------------------
// 3. ELL build: candidate cells = (r,c) and (c,r) per edge; bitmask dedup ->
//    colidx[i][pos], cnt[i]. mask/cnt/colidx pre-zeroed.
// ---------------------------------------------------------------------------
__global__ void build_cells(const int* __restrict__ edges,
                            unsigned* __restrict__ mask,
                            int* __restrict__ colidx,
                            int* __restrict__ cnt) {
    int e = blockIdx.x * blockDim.x + threadIdx.x;
    if (e >= 2 * NEDGE) return;
    int i, j;
    if (e < NEDGE) { i = edges[e];              j = edges[NEDGE + e]; }
    else           { int k = e - NEDGE; i = edges[NEDGE + k]; j = edges[k]; }
    int cell = i * N_NODES + j;
    unsigned bit = 1u << (cell & 31);
    unsigned old = atomicOr(mask + (cell >> 5), bit);
    if (!(old & bit)) {
        int pos = atomicAdd(cnt + i, 1);
        if (pos < CAP) colidx[(size_t)i * CAP + pos] = j;
    }
}

// ---------------------------------------------------------------------------
// 4. Fill ELL entries: L[i,j] = -a_n*exp(-i*Theta) from dense A.
//    ent is pre-zeroed, so every slot spmm could read is defined.
// ---------------------------------------------------------------------------
__global__ __launch_bounds__(256) void fill_ell(const int* __restrict__ colidx,
                                                const int* __restrict__ cnt,
                                                const float* __restrict__ A,
                                                const float* __restrict__ dinv,
                                                const float* __restrict__ qptr,
                                                Entry* __restrict__ ent) {
    int idx = blockIdx.x * 256 + threadIdx.x;     // 0 .. 4096*CAP-1
    int i = idx >> 9;                             // CAP = 512
    int p = idx & (CAP - 1);
    int n = cnt[i]; if (n > CAP) n = CAP;
    if (p >= n) return;
    int j = colidx[(size_t)i * CAP + p] & 4095;
    float a = A[(size_t)i * N_NODES + j];
    float b = A[(size_t)j * N_NODES + i];
    float an = 0.5f * (a + b) * dinv[i] * dinv[j];
    float s, c;
    sincosf(TWO_PI_F * qptr[0] * (a - b), &s, &c);
    Entry en; en.lr = -an * c; en.li = an * s; en.col = j; en.pad = 0;
    ent[(size_t)i * CAP + p] = en;
}

// ---------------------------------------------------------------------------
// 5. Cast X -> planar bf16 (wapply input) + interleaved bf16 (spmm input)
// ---------------------------------------------------------------------------
__global__ __launch_bounds__(256) void cast_in2(const float* __restrict__ Xr,
                                                const float* __restrict__ Xi,
                                                bf16* __restrict__ Xr16,
                                                bf16* __restrict__ Xi16,
                                                bf16* __restrict__ XC) {
    int idx = blockIdx.x * 256 + threadIdx.x;     // n*256+f
    float vr = Xr[idx], vi = Xi[idx];
    Xr16[idx] = (bf16)vr; Xi16[idx] = (bf16)vi;
    bf16x2 p; p[0] = (bf16)vr; p[1] = (bf16)vi;
    ((bf16x2*)XC)[idx] = p;
}

// cast W [3][256][256] -> Wt bf16 [256][768], Wt[n][o*256+k] = W[o][k][n]
__global__ __launch_bounds__(256) void cast_w(const float* __restrict__ W,
                                              bf16* __restrict__ Wt) {
    int idx = blockIdx.x * 256 + threadIdx.x;
    if (idx < 256 * 768) {
        int nout = idx / 768, kk = idx - nout * 768;
        int o = kk >> 8, k = kk & 255;
        Wt[idx] = (bf16)W[((size_t)o * 256 + k) * 256 + nout];
    }
}

// ---------------------------------------------------------------------------
// 6. Sparse complex SpMM (ELL), v2: one block (4 waves) per row.
//    Waves split entries 4-way (wave-strided), unroll-by-2 for 2 outstanding
//    XC gathers; LDS float4 reduce; epilogue in wave 0.
//    Z = alpha*(Lc @ Xc) + beta*C0 (C0 = interleaved bf16, same layout as XC).
// ---------------------------------------------------------------------------
__global__ __launch_bounds__(256) void spmm_k(
    const int* __restrict__ cnt, const Entry* __restrict__ ent,
    const bf16* __restrict__ XC,
    const bf16* __restrict__ C0C,
    float alpha, float beta,
    bf16* __restrict__ Zr, bf16* __restrict__ Zi, bf16* __restrict__ ZC)
{
    __shared__ f32x4 redR[3][64];
    __shared__ f32x4 redI[3][64];

    const int wave = threadIdx.x >> 6, lane = threadIdx.x & 63;
    const int row = blockIdx.x;
    int n1 = cnt[row]; if (n1 > CAP) n1 = CAP;
    const Entry* erow = ent + (size_t)row * CAP;

    float ar[4] = {}, ai[4] = {};
    int e = wave;
    // pairs (e, e+4): 2 independent XC gathers in flight
    for (; e + 4 < n1; e += 8) {
        Entry e0 = erow[e];
        Entry e1 = erow[e + 4];
        bf16x8 x0 = *(const bf16x8*)&XC[(size_t)(e0.col & 4095) * 512 + lane * 8];
        bf16x8 x1 = *(const bf16x8*)&XC[(size_t)(e1.col & 4095) * 512 + lane * 8];
        #pragma unroll
        for (int c = 0; c < 4; ++c) {
            float xr0 = (float)x0[2 * c], xi0 = (float)x0[2 * c + 1];
            ar[c] += e0.lr * xr0 - e0.li * xi0;
            ai[c] += e0.lr * xi0 + e0.li * xr0;
            float xr1 = (float)x1[2 * c], xi1 = (float)x1[2 * c + 1];
            ar[c] += e1.lr * xr1 - e1.li * xi1;
            ai[c] += e1.lr * xi1 + e1.li * xr1;
        }
    }
    if (e < n1) {
        Entry e0 = erow[e];
        bf16x8 x0 = *(const bf16x8*)&XC[(size_t)(e0.col & 4095) * 512 + lane * 8];
        #pragma unroll
        for (int c = 0; c < 4; ++c) {
            float xr0 = (float)x0[2 * c], xi0 = (float)x0[2 * c + 1];
            ar[c] += e0.lr * xr0 - e0.li * xi0;
            ai[c] += e0.lr * xi0 + e0.li * xr0;
        }
    }

    if (wave != 0) {
        f32x4 r, i;
        #pragma unroll
        for (int c = 0; c < 4; ++c) { r[c] = ar[c]; i[c] = ai[c]; }
        redR[wave - 1][lane] = r;
        redI[wave - 1][lane] = i;
    }
    __syncthreads();
    if (wave != 0) return;

    #pragma unroll
    for (int w = 0; w < 3; ++w) {
        f32x4 r = redR[w][lane], i = redI[w][lane];
        #pragma unroll
        for (int c = 0; c < 4; ++c) { ar[c] += r[c]; ai[c] += i[c]; }
    }

    float vr[4], vi[4];
    if (beta != 0.f) {
        bf16x8 c0 = *(const bf16x8*)&C0C[(size_t)row * 512 + lane * 8];
        #pragma unroll
        for (int c = 0; c < 4; ++c) {
            vr[c] = alpha * ar[c] + beta * (float)c0[2 * c];
            vi[c] = alpha * ai[c] + beta * (float)c0[2 * c + 1];
        }
    } else {
        #pragma unroll
        for (int c = 0; c < 4; ++c) { vr[c] = alpha * ar[c]; vi[c] = alpha * ai[c]; }
    }
    size_t base = (size_t)row * FDIM + lane * 4;
    bf16x4 pr, pi;
    #pragma unroll
    for (int c = 0; c < 4; ++c) { pr[c] = (bf16)vr[c]; pi[c] = (bf16)vi[c]; }
    *(bf16x4*)&Zr[base] = pr;
    *(bf16x4*)&Zi[base] = pi;
    if (ZC) {
        bf16x8 o;
        #pragma unroll
        for (int c = 0; c < 4; ++c) { o[2 * c] = pr[c]; o[2 * c + 1] = pi[c]; }
        *(bf16x8*)&ZC[(size_t)row * 512 + lane * 8] = o;
    }
}

// ---------------------------------------------------------------------------
// 7. wapply via MFMA: S = [Z0|Z1|Z2] @ Wcat (K=768); Or = b - Si; Oi = b + Sr
//    (R3/R7-validated kernel, unchanged.)
// ---------------------------------------------------------------------------
__global__ __launch_bounds__(256) void wapply_mfma(
    const bf16* __restrict__ Z0r, const bf16* __restrict__ Z0i,
    const bf16* __restrict__ Z1r, const bf16* __restrict__ Z1i,
    const bf16* __restrict__ Z2r, const bf16* __restrict__ Z2i,
    const bf16* __restrict__ Wt,      // [256][768]
    const float* __restrict__ bias,   // [256]
    float* __restrict__ O32r, float* __restrict__ O32i,
    bf16* __restrict__ O16r_r, bf16* __restrict__ O16r_i,
    bf16* __restrict__ OC)
{
    __shared__ __align__(16) bf16 sZr[64 * 32];
    __shared__ __align__(16) bf16 sZi[64 * 32];
    __shared__ __align__(16) bf16 sW [64 * 32];

    const int tid  = threadIdx.x;
    const int wave = tid >> 6;
    const int lane = tid & 63;
    const int rowBase = blockIdx.y * 64;
    const int colBase = blockIdx.x * 64;

    const int srow = lane >> 2;
    const int skc  = (lane & 3) * 8;

    f32x4 accSr[2][2] = {}, accSi[2][2] = {};
    const int wm = wave & 1, wn = wave >> 1;
    const int fr = lane & 15;
    const int fk = (lane >> 4) * 8;

    for (int kb = 0; kb < 3 * FDIM; kb += 32) {
        int order = kb >> 8;
        int kloc  = kb & 255;
        if (wave == 0 || wave == 1) {
            const bf16* z;
            if (wave == 0) z = (order == 0) ? Z0r : (order == 1) ? Z1r : Z2r;
            else           z = (order == 0) ? Z0i : (order == 1) ? Z1i : Z2i;
            bf16* s = (wave == 0) ? sZr : sZi;
            const bf16* g = z + (size_t)(rowBase + srow) * FDIM + kloc + skc;
            #pragma unroll
            for (int t = 0; t < 4; ++t)
                gld_lds16(g + (size_t)t * 16 * FDIM, s + t * 512);
        } else if (wave == 2) {
            const bf16* g = Wt + (size_t)(colBase + srow) * 768 + kb + skc;
            #pragma unroll
            for (int t = 0; t < 4; ++t)
                gld_lds16(g + (size_t)t * 16 * 768, sW + t * 512);
        }
        __syncthreads();

        bf16x8 zr[2], zi[2], wv[2];
        #pragma unroll
        for (int m = 0; m < 2; ++m) {
            int r = wm * 32 + m * 16 + fr;
            zr[m] = *(const bf16x8*)&sZr[r * 32 + fk];
            zi[m] = *(const bf16x8*)&sZi[r * 32 + fk];
        }
        #pragma unroll
        for (int n = 0; n < 2; ++n) {
            int c = wn * 32 + n * 16 + fr;
            wv[n] = *(const bf16x8*)&sW[c * 32 + fk];
        }
        #pragma unroll
        for (int m = 0; m < 2; ++m)
            #pragma unroll
            for (int n = 0; n < 2; ++n) {
                accSr[m][n] = __builtin_amdgcn_mfma_f32_16x16x32_bf16(zr[m], wv[n], accSr[m][n], 0, 0, 0);
                accSi[m][n] = __builtin_amdgcn_mfma_f32_16x16x32_bf16(zi[m], wv[n], accSi[m][n], 0, 0, 0);
            }
        __syncthreads();
    }

    #pragma unroll
    for (int m = 0; m < 2; ++m)
        #pragma unroll
        for (int n = 0; n < 2; ++n) {
            int row0 = rowBase + wm * 32 + m * 16 + (lane >> 4) * 4;
            int col  = colBase + wn * 32 + n * 16 + (lane & 15);
            float bv = bias[col];
            #pragma unroll
            for (int r = 0; r < 4; ++r) {
                float vr = bv - accSi[m][n][r];
                float vi = bv + accSr[m][n][r];
                int row = row0 + r;
                size_t idx = (size_t)row * FDIM + col;
                if (O32r) {
                    O32r[idx] = vr; O32i[idx] = vi;
                }
                if (O16r_r) {
                    O16r_r[idx] = (bf16)vr; O16r_i[idx] = (bf16)vi;
                }
                if (OC) {
                    bf16x2 p; p[0] = (bf16)vr; p[1] = (bf16)vi;
                    ((bf16x2*)OC)[idx] = p;
                }
            }
        }
}

// ---------------------------------------------------------------------------
// 8. Head (R3/R7-proven): logits = [r,i] @ Wc^T + bc; out = log_softmax.
// ---------------------------------------------------------------------------
__global__ __launch_bounds__(64) void head_k(
    const float* __restrict__ Yr, const float* __restrict__ Yi,
    const float* __restrict__ Wc,   // [40][512]
    const float* __restrict__ bc,   // [40]
    float* __restrict__ out)        // [N][40]
{
    int n = blockIdx.x;
    int t = threadIdx.x;
    __shared__ float x[2 * FDIM];
    for (int k = t; k < FDIM; k += 64) {
        x[k]        = Yr[(size_t)n * FDIM + k];
        x[FDIM + k] = Yi[(size_t)n * FDIM + k];
    }
    __syncthreads();

    float logit = -INFINITY;
    if (t < CDIM) {
        float s = bc[t];
        const float* w = Wc + (size_t)t * (2 * FDIM);
        #pragma unroll 8
        for (int k = 0; k < 2 * FDIM; ++k) s += x[k] * w[k];
        logit = s;
    }
    float m = logit;
    for (int off = 32; off; off >>= 1) m = fmaxf(m, __shfl_down(m, off));
    m = __shfl(m, 0);
    float e = (t < CDIM) ? expf(logit - m) : 0.f;
    float se = e;
    for (int off = 32; off; off >>= 1) se += __shfl_down(se, off);
    se = __shfl(se, 0);
    float lse = m + logf(se);
    if (t < CDIM) out[(size_t)n * CDIM + t] = logit - lse;
}

// ---------------------------------------------------------------------------
// Launcher
// ---------------------------------------------------------------------------
extern "C" void kernel_launch(void* const* d_in, const int* in_sizes, int n_in,
                              void* d_out, int out_size, void* d_ws, size_t ws_size,
                              hipStream_t stream) {
    const float* real = (const float*)d_in[0];
    const float* imag = (const float*)d_in[1];
    const int*   edges = (const int*)d_in[2];
    const float* q    = (const float*)d_in[3];
    const float* ew   = (const float*)d_in[4];
    const float* W1   = (const float*)d_in[5];
    const float* b1   = (const float*)d_in[6];
    const float* W2   = (const float*)d_in[7];
    const float* b2   = (const float*)d_in[8];
    const float* Wc   = (const float*)d_in[9];
    const float* bc   = (const float*)d_in[10];
    float* out = (float*)d_out;

    // ---- workspace carve-up ----
    // Zeroed region (single memset): A, mask, cnt, rowsum, colsum, colidx, ent.
    char* w = (char*)d_ws;
    float*    A      = (float*)w;    w += NN * 4;                        // 64 MB
    unsigned* mask   = (unsigned*)w; w += (NN / 32) * sizeof(unsigned);  // 2 MB
    int*      cnt    = (int*)w;      w += N_NODES * 4;
    float*    rowsum = (float*)w;    w += N_NODES * 4;
    float*    colsum = (float*)w;    w += N_NODES * 4;
    int*      colidx = (int*)w;      w += (size_t)N_NODES * CAP * 4;     // 8 MB
    Entry*    ent    = (Entry*)w;    w += (size_t)N_NODES * CAP * 16;    // 32 MB
    size_t zero_bytes = (size_t)((char*)w - (char*)d_ws);
    // Non-zeroed:
    float* dinv  = (float*)w; w += N_NODES * 4;
    bf16* Xr16 = (bf16*)w; w += NF * 2;
    bf16* Xi16 = (bf16*)w; w += NF * 2;
    bf16* XC   = (bf16*)w; w += NF * 4;                                  // interleaved
    bf16* Z1r  = (bf16*)w; w += NF * 2;
    bf16* Z1i  = (bf16*)w; w += NF * 2;
    bf16* Z1C  = (bf16*)w; w += NF * 4;
    bf16* Z2r  = (bf16*)w; w += NF * 2;
    bf16* Z2i  = (bf16*)w; w += NF * 2;
    float* Y1r32 = (float*)w; w += NF * 4;
    float* Y1i32 = (float*)w; w += NF * 4;
    bf16* Y1rb = (bf16*)w; w += NF * 2;
    bf16* Y1ib = (bf16*)w; w += NF * 2;
    bf16* Y1C  = (bf16*)w; w += NF * 4;
    float* Y2r32 = (float*)w; w += NF * 4;
    float* Y2i32 = (float*)w; w += NF * 4;
    bf16* W1t  = (bf16*)w; w += 256 * 768 * 2;
    bf16* W2t  = (bf16*)w; w += 256 * 768 * 2;

    hipMemsetAsync(d_ws, 0, zero_bytes, stream);

    // ---- build sparse L (ELL) ----
    scatter_deg<<<(NEDGE + 255) / 256, 256, 0, stream>>>(edges, ew, A, rowsum, colsum);
    dinv_k<<<16, 256, 0, stream>>>(rowsum, colsum, dinv);
    build_cells<<<(2 * NEDGE + 255) / 256, 256, 0, stream>>>(edges, mask, colidx, cnt);
    fill_ell<<<(N_NODES * CAP) / 256, 256, 0, stream>>>(colidx, cnt, A, dinv, q, ent);

    // ---- casts ----
    cast_in2<<<NF / 256, 256, 0, stream>>>(real, imag, Xr16, Xi16, XC);
    cast_w<<<768, 256, 0, stream>>>(W1, W1t);
    cast_w<<<768, 256, 0, stream>>>(W2, W2t);

    dim3 gW(FDIM / 64, N_NODES / 64);   // (4, 64)

    // ---- Layer 1 ----
    spmm_k<<<N_NODES, 256, 0, stream>>>(cnt, ent, XC, nullptr,
                                        1.f, 0.f, Z1r, Z1i, Z1C);
    spmm_k<<<N_NODES, 256, 0, stream>>>(cnt, ent, Z1C, XC,
                                        2.f, -1.f, Z2r, Z2i, nullptr);
    wapply_mfma<<<gW, 256, 0, stream>>>(Xr16, Xi16, Z1r, Z1i, Z2r, Z2i,
                                        W1t, b1,
                                        Y1r32, Y1i32,
                                        Y1rb, Y1ib,
                                        Y1C);

    // ---- Layer 2 ----
    spmm_k<<<N_NODES, 256, 0, stream>>>(cnt, ent, Y1C, nullptr,
                                        1.f, 0.f, Z1r, Z1i, Z1C);
    spmm_k<<<N_NODES, 256, 0, stream>>>(cnt, ent, Z1C, Y1C,
                                        2.f, -1.f, Z2r, Z2i, nullptr);
    wapply_mfma<<<gW, 256, 0, stream>>>(Y1rb, Y1ib, Z1r, Z1i, Z2r, Z2i,
                                        W2t, b2,
                                        Y2r32, Y2i32,
                                        nullptr, nullptr,
                                        nullptr);

    // ---- Head ----
    head_k<<<N_NODES, 64, 0, stream>>>(Y2r32, Y2i32, Wc, bc, out);
}

// Round 9
// 335.462 us; speedup vs baseline: 1.6522x; 1.0070x over previous
//
#include <hip/hip_runtime.h>
#include <cmath>

#define N_NODES 4096
#define FDIM    256
#define CDIM    40
#define NEDGE   131072
#define CAP     512                  // ELL row capacity (row nnz ~Poisson(64))
#define TWO_PI_F 6.28318530717958647692f

typedef __bf16 bf16;
typedef __bf16 bf16x2 __attribute__((ext_vector_type(2)));
typedef __bf16 bf16x4 __attribute__((ext_vector_type(4)));
typedef __bf16 bf16x8 __attribute__((ext_vector_type(8)));
typedef float  f32x4  __attribute__((ext_vector_type(4)));

static constexpr size_t NN = (size_t)N_NODES * N_NODES;   // 16,777,216
static constexpr size_t NF = (size_t)N_NODES * FDIM;      // 1,048,576

struct __align__(16) Entry { float lr, li; int col, pad; };

// async global->LDS, 16B per lane, dest = ldsBase + lane*16
__device__ __forceinline__ void gld_lds16(const bf16* g, bf16* s) {
    __builtin_amdgcn_global_load_lds(
        (const __attribute__((address_space(1))) void*)g,
        (__attribute__((address_space(3))) void*)s,
        16, 0, 0);
}

// ---------------------------------------------------------------------------
// 1. Scatter edges into dense A + accumulate raw row/col sums (all pre-zeroed)
// ---------------------------------------------------------------------------
__global__ void scatter_deg(const int* __restrict__ edges,
                            const float* __restrict__ w,
                            float* __restrict__ A,
                            float* __restrict__ rowsum,
                            float* __restrict__ colsum) {
    int e = blockIdx.x * blockDim.x + threadIdx.x;
    if (e < NEDGE) {
        int r = edges[e];
        int c = edges[NEDGE + e];
        float wv = w[e];
        atomicAdd(A + (size_t)r * N_NODES + c, wv);
        atomicAdd(rowsum + r, wv);
        atomicAdd(colsum + c, wv);
    }
}

// 2. dinv = (0.5*(rowsum+colsum))^-0.5 with 0 -> 1
__global__ void dinv_k(const float* __restrict__ rowsum,
                       const float* __restrict__ colsum,
                       float* __restrict__ dinv) {
    int j = blockIdx.x * blockDim.x + threadIdx.x;
    if (j < N_NODES) {
        float d = 0.5f * (rowsum[j] + colsum[j]);
        if (d == 0.f) d = 1.f;
        dinv[j] = 1.0f / sqrtf(d);
    }
}

// ---------------------------------------------------------------------------
// 3. ELL build: candidate cells = (r,c) and (c,r) per edge; bitmask dedup ->
//    colidx[i][pos], cnt[i]. mask/cnt pre-zeroed. colidx needs no zeroing:
//    every slot fill_ell reads (p < min(cnt,CAP)) is written here.
// ---------------------------------------------------------------------------
__global__ void build_cells(const int* __restrict__ edges,
                            unsigned* __restrict__ mask,
                            int* __restrict__ colidx,
                            int* __restrict__ cnt) {
    int e = blockIdx.x * blockDim.x + threadIdx.x;
    if (e >= 2 * NEDGE) return;
    int i, j;
    if (e < NEDGE) { i = edges[e];              j = edges[NEDGE + e]; }
    else           { int k = e - NEDGE; i = edges[NEDGE + k]; j = edges[k]; }
    int cell = i * N_NODES + j;
    unsigned bit = 1u << (cell & 31);
    unsigned old = atomicOr(mask + (cell >> 5), bit);
    if (!(old & bit)) {
        int pos = atomicAdd(cnt + i, 1);
        if (pos < CAP) colidx[(size_t)i * CAP + pos] = j;
    }
}

// ---------------------------------------------------------------------------
// 4. Fill ELL entries: L[i,j] = -a_n*exp(-i*Theta) from dense A.
//    ent is pre-zeroed, so every slot spmm could read is defined.
// ---------------------------------------------------------------------------
__global__ __launch_bounds__(256) void fill_ell(const int* __restrict__ colidx,
                                                const int* __restrict__ cnt,
                                                const float* __restrict__ A,
                                                const float* __restrict__ dinv,
                                                const float* __restrict__ qptr,
                                                Entry* __restrict__ ent) {
    int idx = blockIdx.x * 256 + threadIdx.x;     // 0 .. 4096*CAP-1
    int i = idx >> 9;                             // CAP = 512
    int p = idx & (CAP - 1);
    int n = cnt[i]; if (n > CAP) n = CAP;
    if (p >= n) return;
    int j = colidx[(size_t)i * CAP + p] & 4095;
    float a = A[(size_t)i * N_NODES + j];
    float b = A[(size_t)j * N_NODES + i];
    float an = 0.5f * (a + b) * dinv[i] * dinv[j];
    float s, c;
    sincosf(TWO_PI_F * qptr[0] * (a - b), &s, &c);
    Entry en; en.lr = -an * c; en.li = an * s; en.col = j; en.pad = 0;
    ent[(size_t)i * CAP + p] = en;
}

// ---------------------------------------------------------------------------
// 5. Cast X -> planar bf16 (wapply input) + interleaved bf16 (spmm input)
// ---------------------------------------------------------------------------
__global__ __launch_bounds__(256) void cast_in2(const float* __restrict__ Xr,
                                                const float* __restrict__ Xi,
                                                bf16* __restrict__ Xr16,
                                                bf16* __restrict__ Xi16,
                                                bf16* __restrict__ XC) {
    int idx = blockIdx.x * 256 + threadIdx.x;     // n*256+f
    float vr = Xr[idx], vi = Xi[idx];
    Xr16[idx] = (bf16)vr; Xi16[idx] = (bf16)vi;
    bf16x2 p; p[0] = (bf16)vr; p[1] = (bf16)vi;
    ((bf16x2*)XC)[idx] = p;
}

// cast W [3][256][256] -> Wt bf16 [256][768], Wt[n][o*256+k] = W[o][k][n]
__global__ __launch_bounds__(256) void cast_w(const float* __restrict__ W,
                                              bf16* __restrict__ Wt) {
    int idx = blockIdx.x * 256 + threadIdx.x;
    if (idx < 256 * 768) {
        int nout = idx / 768, kk = idx - nout * 768;
        int o = kk >> 8, k = kk & 255;
        Wt[idx] = (bf16)W[((size_t)o * 256 + k) * 256 + nout];
    }
}

// ---------------------------------------------------------------------------
// 6. Sparse complex SpMM (ELL), v2: one block (4 waves) per row.
//    Waves split entries 4-way (wave-strided), unroll-by-2 for 2 outstanding
//    XC gathers; LDS float4 reduce; epilogue in wave 0.
//    Z = alpha*(Lc @ Xc) + beta*C0 (C0 = interleaved bf16, same layout as XC).
// ---------------------------------------------------------------------------
__global__ __launch_bounds__(256) void spmm_k(
    const int* __restrict__ cnt, const Entry* __restrict__ ent,
    const bf16* __restrict__ XC,
    const bf16* __restrict__ C0C,
    float alpha, float beta,
    bf16* __restrict__ Zr, bf16* __restrict__ Zi, bf16* __restrict__ ZC)
{
    __shared__ f32x4 redR[3][64];
    __shared__ f32x4 redI[3][64];

    const int wave = threadIdx.x >> 6, lane = threadIdx.x & 63;
    const int row = blockIdx.x;
    int n1 = cnt[row]; if (n1 > CAP) n1 = CAP;
    const Entry* erow = ent + (size_t)row * CAP;

    float ar[4] = {}, ai[4] = {};
    int e = wave;
    // pairs (e, e+4): 2 independent XC gathers in flight
    for (; e + 4 < n1; e += 8) {
        Entry e0 = erow[e];
        Entry e1 = erow[e + 4];
        bf16x8 x0 = *(const bf16x8*)&XC[(size_t)(e0.col & 4095) * 512 + lane * 8];
        bf16x8 x1 = *(const bf16x8*)&XC[(size_t)(e1.col & 4095) * 512 + lane * 8];
        #pragma unroll
        for (int c = 0; c < 4; ++c) {
            float xr0 = (float)x0[2 * c], xi0 = (float)x0[2 * c + 1];
            ar[c] += e0.lr * xr0 - e0.li * xi0;
            ai[c] += e0.lr * xi0 + e0.li * xr0;
            float xr1 = (float)x1[2 * c], xi1 = (float)x1[2 * c + 1];
            ar[c] += e1.lr * xr1 - e1.li * xi1;
            ai[c] += e1.lr * xi1 + e1.li * xr1;
        }
    }
    if (e < n1) {
        Entry e0 = erow[e];
        bf16x8 x0 = *(const bf16x8*)&XC[(size_t)(e0.col & 4095) * 512 + lane * 8];
        #pragma unroll
        for (int c = 0; c < 4; ++c) {
            float xr0 = (float)x0[2 * c], xi0 = (float)x0[2 * c + 1];
            ar[c] += e0.lr * xr0 - e0.li * xi0;
            ai[c] += e0.lr * xi0 + e0.li * xr0;
        }
    }

    if (wave != 0) {
        f32x4 r, i;
        #pragma unroll
        for (int c = 0; c < 4; ++c) { r[c] = ar[c]; i[c] = ai[c]; }
        redR[wave - 1][lane] = r;
        redI[wave - 1][lane] = i;
    }
    __syncthreads();
    if (wave != 0) return;

    #pragma unroll
    for (int w = 0; w < 3; ++w) {
        f32x4 r = redR[w][lane], i = redI[w][lane];
        #pragma unroll
        for (int c = 0; c < 4; ++c) { ar[c] += r[c]; ai[c] += i[c]; }
    }

    float vr[4], vi[4];
    if (beta != 0.f) {
        bf16x8 c0 = *(const bf16x8*)&C0C[(size_t)row * 512 + lane * 8];
        #pragma unroll
        for (int c = 0; c < 4; ++c) {
            vr[c] = alpha * ar[c] + beta * (float)c0[2 * c];
            vi[c] = alpha * ai[c] + beta * (float)c0[2 * c + 1];
        }
    } else {
        #pragma unroll
        for (int c = 0; c < 4; ++c) { vr[c] = alpha * ar[c]; vi[c] = alpha * ai[c]; }
    }
    size_t base = (size_t)row * FDIM + lane * 4;
    bf16x4 pr, pi;
    #pragma unroll
    for (int c = 0; c < 4; ++c) { pr[c] = (bf16)vr[c]; pi[c] = (bf16)vi[c]; }
    *(bf16x4*)&Zr[base] = pr;
    *(bf16x4*)&Zi[base] = pi;
    if (ZC) {
        bf16x8 o;
        #pragma unroll
        for (int c = 0; c < 4; ++c) { o[2 * c] = pr[c]; o[2 * c + 1] = pi[c]; }
        *(bf16x8*)&ZC[(size_t)row * 512 + lane * 8] = o;
    }
}

// ---------------------------------------------------------------------------
// 7. wapply via MFMA: S = [Z0|Z1|Z2] @ Wcat (K=768); Or = b - Si; Oi = b + Sr
//    (R3/R7-validated kernel, unchanged.)
// ---------------------------------------------------------------------------
__global__ __launch_bounds__(256) void wapply_mfma(
    const bf16* __restrict__ Z0r, const bf16* __restrict__ Z0i,
    const bf16* __restrict__ Z1r, const bf16* __restrict__ Z1i,
    const bf16* __restrict__ Z2r, const bf16* __restrict__ Z2i,
    const bf16* __restrict__ Wt,      // [256][768]
    const float* __restrict__ bias,   // [256]
    float* __restrict__ O32r, float* __restrict__ O32i,
    bf16* __restrict__ O16r_r, bf16* __restrict__ O16r_i,
    bf16* __restrict__ OC)
{
    __shared__ __align__(16) bf16 sZr[64 * 32];
    __shared__ __align__(16) bf16 sZi[64 * 32];
    __shared__ __align__(16) bf16 sW [64 * 32];

    const int tid  = threadIdx.x;
    const int wave = tid >> 6;
    const int lane = tid & 63;
    const int rowBase = blockIdx.y * 64;
    const int colBase = blockIdx.x * 64;

    const int srow = lane >> 2;
    const int skc  = (lane & 3) * 8;

    f32x4 accSr[2][2] = {}, accSi[2][2] = {};
    const int wm = wave & 1, wn = wave >> 1;
    const int fr = lane & 15;
    const int fk = (lane >> 4) * 8;

    for (int kb = 0; kb < 3 * FDIM; kb += 32) {
        int order = kb >> 8;
        int kloc  = kb & 255;
        if (wave == 0 || wave == 1) {
            const bf16* z;
            if (wave == 0) z = (order == 0) ? Z0r : (order == 1) ? Z1r : Z2r;
            else           z = (order == 0) ? Z0i : (order == 1) ? Z1i : Z2i;
            bf16* s = (wave == 0) ? sZr : sZi;
            const bf16* g = z + (size_t)(rowBase + srow) * FDIM + kloc + skc;
            #pragma unroll
            for (int t = 0; t < 4; ++t)
                gld_lds16(g + (size_t)t * 16 * FDIM, s + t * 512);
        } else if (wave == 2) {
            const bf16* g = Wt + (size_t)(colBase + srow) * 768 + kb + skc;
            #pragma unroll
            for (int t = 0; t < 4; ++t)
                gld_lds16(g + (size_t)t * 16 * 768, sW + t * 512);
        }
        __syncthreads();

        bf16x8 zr[2], zi[2], wv[2];
        #pragma unroll
        for (int m = 0; m < 2; ++m) {
            int r = wm * 32 + m * 16 + fr;
            zr[m] = *(const bf16x8*)&sZr[r * 32 + fk];
            zi[m] = *(const bf16x8*)&sZi[r * 32 + fk];
        }
        #pragma unroll
        for (int n = 0; n < 2; ++n) {
            int c = wn * 32 + n * 16 + fr;
            wv[n] = *(const bf16x8*)&sW[c * 32 + fk];
        }
        #pragma unroll
        for (int m = 0; m < 2; ++m)
            #pragma unroll
            for (int n = 0; n < 2; ++n) {
                accSr[m][n] = __builtin_amdgcn_mfma_f32_16x16x32_bf16(zr[m], wv[n], accSr[m][n], 0, 0, 0);
                accSi[m][n] = __builtin_amdgcn_mfma_f32_16x16x32_bf16(zi[m], wv[n], accSi[m][n], 0, 0, 0);
            }
        __syncthreads();
    }

    #pragma unroll
    for (int m = 0; m < 2; ++m)
        #pragma unroll
        for (int n = 0; n < 2; ++n) {
            int row0 = rowBase + wm * 32 + m * 16 + (lane >> 4) * 4;
            int col  = colBase + wn * 32 + n * 16 + (lane & 15);
            float bv = bias[col];
            #pragma unroll
            for (int r = 0; r < 4; ++r) {
                float vr = bv - accSi[m][n][r];
                float vi = bv + accSr[m][n][r];
                int row = row0 + r;
                size_t idx = (size_t)row * FDIM + col;
                if (O32r) {
                    O32r[idx] = vr; O32i[idx] = vi;
                }
                if (O16r_r) {
                    O16r_r[idx] = (bf16)vr; O16r_i[idx] = (bf16)vi;
                }
                if (OC) {
                    bf16x2 p; p[0] = (bf16)vr; p[1] = (bf16)vi;
                    ((bf16x2*)OC)[idx] = p;
                }
            }
        }
}

// ---------------------------------------------------------------------------
// 8. Head v2: logits = [r,i] @ Wc^T + bc; out = log_softmax.
//    One wave per row; 8 independent accumulators break the serial FMA chain;
//    float4 W loads (Wc L2-resident, 80 KB).
// ---------------------------------------------------------------------------
__global__ __launch_bounds__(64) void head_k(
    const float* __restrict__ Yr, const float* __restrict__ Yi,
    const float* __restrict__ Wc,   // [40][512]
    const float* __restrict__ bc,   // [40]
    float* __restrict__ out)        // [N][40]
{
    int n = blockIdx.x;
    int t = threadIdx.x;
    __shared__ float x[2 * FDIM];
    for (int k = t; k < FDIM; k += 64) {
        x[k]        = Yr[(size_t)n * FDIM + k];
        x[FDIM + k] = Yi[(size_t)n * FDIM + k];
    }
    __syncthreads();

    float logit = -INFINITY;
    if (t < CDIM) {
        const float* w = Wc + (size_t)t * (2 * FDIM);
        float acc[8] = {};
        #pragma unroll 4
        for (int k = 0; k < 2 * FDIM; k += 8) {
            f32x4 wa = *(const f32x4*)&w[k];
            f32x4 wb = *(const f32x4*)&w[k + 4];
            f32x4 xa = *(const f32x4*)&x[k];
            f32x4 xb = *(const f32x4*)&x[k + 4];
            acc[0] += xa[0] * wa[0]; acc[1] += xa[1] * wa[1];
            acc[2] += xa[2] * wa[2]; acc[3] += xa[3] * wa[3];
            acc[4] += xb[0] * wb[0]; acc[5] += xb[1] * wb[1];
            acc[6] += xb[2] * wb[2]; acc[7] += xb[3] * wb[3];
        }
        logit = bc[t] + ((acc[0] + acc[1]) + (acc[2] + acc[3]))
                      + ((acc[4] + acc[5]) + (acc[6] + acc[7]));
    }
    float m = logit;
    for (int off = 32; off; off >>= 1) m = fmaxf(m, __shfl_down(m, off));
    m = __shfl(m, 0);
    float e = (t < CDIM) ? expf(logit - m) : 0.f;
    float se = e;
    for (int off = 32; off; off >>= 1) se += __shfl_down(se, off);
    se = __shfl(se, 0);
    float lse = m + logf(se);
    if (t < CDIM) out[(size_t)n * CDIM + t] = logit - lse;
}

// ---------------------------------------------------------------------------
// Launcher
// ---------------------------------------------------------------------------
extern "C" void kernel_launch(void* const* d_in, const int* in_sizes, int n_in,
                              void* d_out, int out_size, void* d_ws, size_t ws_size,
                              hipStream_t stream) {
    const float* real = (const float*)d_in[0];
    const float* imag = (const float*)d_in[1];
    const int*   edges = (const int*)d_in[2];
    const float* q    = (const float*)d_in[3];
    const float* ew   = (const float*)d_in[4];
    const float* W1   = (const float*)d_in[5];
    const float* b1   = (const float*)d_in[6];
    const float* W2   = (const float*)d_in[7];
    const float* b2   = (const float*)d_in[8];
    const float* Wc   = (const float*)d_in[9];
    const float* bc   = (const float*)d_in[10];
    float* out = (float*)d_out;

    // ---- workspace carve-up ----
    // Zeroed region (single memset): A, mask, cnt, rowsum, colsum, ent.
    char* w = (char*)d_ws;
    float*    A      = (float*)w;    w += NN * 4;                        // 64 MB
    unsigned* mask   = (unsigned*)w; w += (NN / 32) * sizeof(unsigned);  // 2 MB
    int*      cnt    = (int*)w;      w += N_NODES * 4;
    float*    rowsum = (float*)w;    w += N_NODES * 4;
    float*    colsum = (float*)w;    w += N_NODES * 4;
    Entry*    ent    = (Entry*)w;    w += (size_t)N_NODES * CAP * 16;    // 32 MB
    size_t zero_bytes = (size_t)((char*)w - (char*)d_ws);
    // Non-zeroed:
    int*   colidx = (int*)w; w += (size_t)N_NODES * CAP * 4;             // 8 MB
    float* dinv  = (float*)w; w += N_NODES * 4;
    bf16* Xr16 = (bf16*)w; w += NF * 2;
    bf16* Xi16 = (bf16*)w; w += NF * 2;
    bf16* XC   = (bf16*)w; w += NF * 4;                                  // interleaved
    bf16* Z1r  = (bf16*)w; w += NF * 2;
    bf16* Z1i  = (bf16*)w; w += NF * 2;
    bf16* Z1C  = (bf16*)w; w += NF * 4;
    bf16* Z2r  = (bf16*)w; w += NF * 2;
    bf16* Z2i  = (bf16*)w; w += NF * 2;
    float* Y1r32 = (float*)w; w += NF * 4;
    float* Y1i32 = (float*)w; w += NF * 4;
    bf16* Y1rb = (bf16*)w; w += NF * 2;
    bf16* Y1ib = (bf16*)w; w += NF * 2;
    bf16* Y1C  = (bf16*)w; w += NF * 4;
    float* Y2r32 = (float*)w; w += NF * 4;
    float* Y2i32 = (float*)w; w += NF * 4;
    bf16* W1t  = (bf16*)w; w += 256 * 768 * 2;
    bf16* W2t  = (bf16*)w; w += 256 * 768 * 2;

    hipMemsetAsync(d_ws, 0, zero_bytes, stream);

    // ---- build sparse L (ELL) ----
    scatter_deg<<<(NEDGE + 255) / 256, 256, 0, stream>>>(edges, ew, A, rowsum, colsum);
    dinv_k<<<16, 256, 0, stream>>>(rowsum, colsum, dinv);
    build_cells<<<(2 * NEDGE + 255) / 256, 256, 0, stream>>>(edges, mask, colidx, cnt);
    fill_ell<<<(N_NODES * CAP) / 256, 256, 0, stream>>>(colidx, cnt, A, dinv, q, ent);

    // ---- casts ----
    cast_in2<<<NF / 256, 256, 0, stream>>>(real, imag, Xr16, Xi16, XC);
    cast_w<<<768, 256, 0, stream>>>(W1, W1t);
    cast_w<<<768, 256, 0, stream>>>(W2, W2t);

    dim3 gW(FDIM / 64, N_NODES / 64);   // (4, 64)

    // ---- Layer 1 ----
    spmm_k<<<N_NODES, 256, 0, stream>>>(cnt, ent, XC, nullptr,
                                        1.f, 0.f, Z1r, Z1i, Z1C);
    spmm_k<<<N_NODES, 256, 0, stream>>>(cnt, ent, Z1C, XC,
                                        2.f, -1.f, Z2r, Z2i, nullptr);
    wapply_mfma<<<gW, 256, 0, stream>>>(Xr16, Xi16, Z1r, Z1i, Z2r, Z2i,
                                        W1t, b1,
                                        Y1r32, Y1i32,
                                        Y1rb, Y1ib,
                                        Y1C);

    // ---- Layer 2 ----
    spmm_k<<<N_NODES, 256, 0, stream>>>(cnt, ent, Y1C, nullptr,
                                        1.f, 0.f, Z1r, Z1i, Z1C);
    spmm_k<<<N_NODES, 256, 0, stream>>>(cnt, ent, Z1C, Y1C,
                                        2.f, -1.f, Z2r, Z2i, nullptr);
    wapply_mfma<<<gW, 256, 0, stream>>>(Y1rb, Y1ib, Z1r, Z1i, Z2r, Z2i,
                                        W2t, b2,
                                        Y2r32, Y2i32,
                                        nullptr, nullptr,
                                        nullptr);

    // ---- Head ----
    head_k<<<N_NODES, 64, 0, stream>>>(Y2r32, Y2i32, Wc, bc, out);
}

// Round 11
// 304.093 us; speedup vs baseline: 1.8227x; 1.1032x over previous
//
#include <hip/hip_runtime.h>
#include <cmath>

#define N_NODES 4096
#define FDIM    256
#define CDIM    40
#define NEDGE   131072
#define CAP     512                  // ELL row capacity (row nnz ~Poisson(64))
#define TWO_PI_F 6.28318530717958647692f

typedef __bf16 bf16;
typedef __bf16 bf16x2 __attribute__((ext_vector_type(2)));
typedef __bf16 bf16x4 __attribute__((ext_vector_type(4)));
typedef __bf16 bf16x8 __attribute__((ext_vector_type(8)));
typedef float  f32x4  __attribute__((ext_vector_type(4)));

static constexpr size_t NN = (size_t)N_NODES * N_NODES;   // 16,777,216
static constexpr size_t NF = (size_t)N_NODES * FDIM;      // 1,048,576

struct __align__(16) Entry { float lr, li; int col, pad; };

// async global->LDS, 16B per lane, dest = ldsBase + lane*16
__device__ __forceinline__ void gld_lds16(const bf16* g, bf16* s) {
    __builtin_amdgcn_global_load_lds(
        (const __attribute__((address_space(1))) void*)g,
        (__attribute__((address_space(3))) void*)s,
        16, 0, 0);
}

// ---------------------------------------------------------------------------
// 1. Scatter edges into dense A + accumulate raw row/col sums (all pre-zeroed)
// ---------------------------------------------------------------------------
__global__ void scatter_deg(const int* __restrict__ edges,
                            const float* __restrict__ w,
                            float* __restrict__ A,
                            float* __restrict__ rowsum,
                            float* __restrict__ colsum) {
    int e = blockIdx.x * blockDim.x + threadIdx.x;
    if (e < NEDGE) {
        int r = edges[e];
        int c = edges[NEDGE + e];
        float wv = w[e];
        atomicAdd(A + (size_t)r * N_NODES + c, wv);
        atomicAdd(rowsum + r, wv);
        atomicAdd(colsum + c, wv);
    }
}

// 2. dinv = (0.5*(rowsum+colsum))^-0.5 with 0 -> 1
__global__ void dinv_k(const float* __restrict__ rowsum,
                       const float* __restrict__ colsum,
                       float* __restrict__ dinv) {
    int j = blockIdx.x * blockDim.x + threadIdx.x;
    if (j < N_NODES) {
        float d = 0.5f * (rowsum[j] + colsum[j]);
        if (d == 0.f) d = 1.f;
        dinv[j] = 1.0f / sqrtf(d);
    }
}

// ---------------------------------------------------------------------------
// 3. ELL build: candidate cells = (r,c) and (c,r) per edge; bitmask dedup ->
//    colidx[i][pos], cnt[i]. mask/cnt pre-zeroed. colidx needs no zeroing:
//    every slot fill_ell reads (p < min(cnt,CAP)) is written here.
// ---------------------------------------------------------------------------
__global__ void build_cells(const int* __restrict__ edges,
                            unsigned* __restrict__ mask,
                            int* __restrict__ colidx,
                            int* __restrict__ cnt) {
    int e = blockIdx.x * blockDim.x + threadIdx.x;
    if (e >= 2 * NEDGE) return;
    int i, j;
    if (e < NEDGE) { i = edges[e];              j = edges[NEDGE + e]; }
    else           { int k = e - NEDGE; i = edges[NEDGE + k]; j = edges[k]; }
    int cell = i * N_NODES + j;
    unsigned bit = 1u << (cell & 31);
    unsigned old = atomicOr(mask + (cell >> 5), bit);
    if (!(old & bit)) {
        int pos = atomicAdd(cnt + i, 1);
        if (pos < CAP) colidx[(size_t)i * CAP + pos] = j;
    }
}

// ---------------------------------------------------------------------------
// 4. Fill ELL entries: L[i,j] = -a_n*exp(-i*Theta) from dense A.
//    ent is pre-zeroed, so every slot spmm could read is defined.
// ---------------------------------------------------------------------------
__global__ __launch_bounds__(256) void fill_ell(const int* __restrict__ colidx,
                                                const int* __restrict__ cnt,
                                                const float* __restrict__ A,
                                                const float* __restrict__ dinv,
                                                const float* __restrict__ qptr,
                                                Entry* __restrict__ ent) {
    int idx = blockIdx.x * 256 + threadIdx.x;     // 0 .. 4096*CAP-1
    int i = idx >> 9;                             // CAP = 512
    int p = idx & (CAP - 1);
    int n = cnt[i]; if (n > CAP) n = CAP;
    if (p >= n) return;
    int j = colidx[(size_t)i * CAP + p] & 4095;
    float a = A[(size_t)i * N_NODES + j];
    float b = A[(size_t)j * N_NODES + i];
    float an = 0.5f * (a + b) * dinv[i] * dinv[j];
    float s, c;
    sincosf(TWO_PI_F * qptr[0] * (a - b), &s, &c);
    Entry en; en.lr = -an * c; en.li = an * s; en.col = j; en.pad = 0;
    ent[(size_t)i * CAP + p] = en;
}

// ---------------------------------------------------------------------------
// 5. Cast X -> planar bf16 (wapply input) + interleaved bf16 (spmm input)
// ---------------------------------------------------------------------------
__global__ __launch_bounds__(256) void cast_in2(const float* __restrict__ Xr,
                                                const float* __restrict__ Xi,
                                                bf16* __restrict__ Xr16,
                                                bf16* __restrict__ Xi16,
                                                bf16* __restrict__ XC) {
    int idx = blockIdx.x * 256 + threadIdx.x;     // n*256+f
    float vr = Xr[idx], vi = Xi[idx];
    Xr16[idx] = (bf16)vr; Xi16[idx] = (bf16)vi;
    bf16x2 p; p[0] = (bf16)vr; p[1] = (bf16)vi;
    ((bf16x2*)XC)[idx] = p;
}

// cast W [3][256][256] -> Wt bf16 [256][768], Wt[n][o*256+k] = W[o][k][n]
__global__ __launch_bounds__(256) void cast_w(const float* __restrict__ W,
                                              bf16* __restrict__ Wt) {
    int idx = blockIdx.x * 256 + threadIdx.x;
    if (idx < 256 * 768) {
        int nout = idx / 768, kk = idx - nout * 768;
        int o = kk >> 8, k = kk & 255;
        Wt[idx] = (bf16)W[((size_t)o * 256 + k) * 256 + nout];
    }
}

// cast Wc [40][512] -> bf16 [48][512], rows 40..47 zero
__global__ __launch_bounds__(256) void cast_wc(const float* __restrict__ Wc,
                                               bf16* __restrict__ Wcb) {
    int idx = blockIdx.x * 256 + threadIdx.x;     // < 48*512
    int row = idx >> 9, k = idx & 511;
    Wcb[idx] = (row < CDIM) ? (bf16)Wc[row * 512 + k] : (bf16)0.f;
}

// ---------------------------------------------------------------------------
// 6. Sparse complex SpMM (ELL), v2: one block (4 waves) per row. (R8-proven.)
// ---------------------------------------------------------------------------
__global__ __launch_bounds__(256) void spmm_k(
    const int* __restrict__ cnt, const Entry* __restrict__ ent,
    const bf16* __restrict__ XC,
    const bf16* __restrict__ C0C,
    float alpha, float beta,
    bf16* __restrict__ Zr, bf16* __restrict__ Zi, bf16* __restrict__ ZC)
{
    __shared__ f32x4 redR[3][64];
    __shared__ f32x4 redI[3][64];

    const int wave = threadIdx.x >> 6, lane = threadIdx.x & 63;
    const int row = blockIdx.x;
    int n1 = cnt[row]; if (n1 > CAP) n1 = CAP;
    const Entry* erow = ent + (size_t)row * CAP;

    float ar[4] = {}, ai[4] = {};
    int e = wave;
    for (; e + 4 < n1; e += 8) {
        Entry e0 = erow[e];
        Entry e1 = erow[e + 4];
        bf16x8 x0 = *(const bf16x8*)&XC[(size_t)(e0.col & 4095) * 512 + lane * 8];
        bf16x8 x1 = *(const bf16x8*)&XC[(size_t)(e1.col & 4095) * 512 + lane * 8];
        #pragma unroll
        for (int c = 0; c < 4; ++c) {
            float xr0 = (float)x0[2 * c], xi0 = (float)x0[2 * c + 1];
            ar[c] += e0.lr * xr0 - e0.li * xi0;
            ai[c] += e0.lr * xi0 + e0.li * xr0;
            float xr1 = (float)x1[2 * c], xi1 = (float)x1[2 * c + 1];
            ar[c] += e1.lr * xr1 - e1.li * xi1;
            ai[c] += e1.lr * xi1 + e1.li * xr1;
        }
    }
    if (e < n1) {
        Entry e0 = erow[e];
        bf16x8 x0 = *(const bf16x8*)&XC[(size_t)(e0.col & 4095) * 512 + lane * 8];
        #pragma unroll
        for (int c = 0; c < 4; ++c) {
            float xr0 = (float)x0[2 * c], xi0 = (float)x0[2 * c + 1];
            ar[c] += e0.lr * xr0 - e0.li * xi0;
            ai[c] += e0.lr * xi0 + e0.li * xr0;
        }
    }

    if (wave != 0) {
        f32x4 r, i;
        #pragma unroll
        for (int c = 0; c < 4; ++c) { r[c] = ar[c]; i[c] = ai[c]; }
        redR[wave - 1][lane] = r;
        redI[wave - 1][lane] = i;
    }
    __syncthreads();
    if (wave != 0) return;

    #pragma unroll
    for (int w = 0; w < 3; ++w) {
        f32x4 r = redR[w][lane], i = redI[w][lane];
        #pragma unroll
        for (int c = 0; c < 4; ++c) { ar[c] += r[c]; ai[c] += i[c]; }
    }

    float vr[4], vi[4];
    if (beta != 0.f) {
        bf16x8 c0 = *(const bf16x8*)&C0C[(size_t)row * 512 + lane * 8];
        #pragma unroll
        for (int c = 0; c < 4; ++c) {
            vr[c] = alpha * ar[c] + beta * (float)c0[2 * c];
            vi[c] = alpha * ai[c] + beta * (float)c0[2 * c + 1];
        }
    } else {
        #pragma unroll
        for (int c = 0; c < 4; ++c) { vr[c] = alpha * ar[c]; vi[c] = alpha * ai[c]; }
    }
    size_t base = (size_t)row * FDIM + lane * 4;
    bf16x4 pr, pi;
    #pragma unroll
    for (int c = 0; c < 4; ++c) { pr[c] = (bf16)vr[c]; pi[c] = (bf16)vi[c]; }
    *(bf16x4*)&Zr[base] = pr;
    *(bf16x4*)&Zi[base] = pi;
    if (ZC) {
        bf16x8 o;
        #pragma unroll
        for (int c = 0; c < 4; ++c) { o[2 * c] = pr[c]; o[2 * c + 1] = pi[c]; }
        *(bf16x8*)&ZC[(size_t)row * 512 + lane * 8] = o;
    }
}

// ---------------------------------------------------------------------------
// 7. wapply via MFMA (R3/R7/R9-validated, byte-identical).
// ---------------------------------------------------------------------------
__global__ __launch_bounds__(256) void wapply_mfma(
    const bf16* __restrict__ Z0r, const bf16* __restrict__ Z0i,
    const bf16* __restrict__ Z1r, const bf16* __restrict__ Z1i,
    const bf16* __restrict__ Z2r, const bf16* __restrict__ Z2i,
    const bf16* __restrict__ Wt,      // [256][768]
    const float* __restrict__ bias,   // [256]
    float* __restrict__ O32r, float* __restrict__ O32i,
    bf16* __restrict__ O16r_r, bf16* __restrict__ O16r_i,
    bf16* __restrict__ OC)
{
    __shared__ __align__(16) bf16 sZr[64 * 32];
    __shared__ __align__(16) bf16 sZi[64 * 32];
    __shared__ __align__(16) bf16 sW [64 * 32];

    const int tid  = threadIdx.x;
    const int wave = tid >> 6;
    const int lane = tid & 63;
    const int rowBase = blockIdx.y * 64;
    const int colBase = blockIdx.x * 64;

    const int srow = lane >> 2;
    const int skc  = (lane & 3) * 8;

    f32x4 accSr[2][2] = {}, accSi[2][2] = {};
    const int wm = wave & 1, wn = wave >> 1;
    const int fr = lane & 15;
    const int fk = (lane >> 4) * 8;

    for (int kb = 0; kb < 3 * FDIM; kb += 32) {
        int order = kb >> 8;
        int kloc  = kb & 255;
        if (wave == 0 || wave == 1) {
            const bf16* z;
            if (wave == 0) z = (order == 0) ? Z0r : (order == 1) ? Z1r : Z2r;
            else           z = (order == 0) ? Z0i : (order == 1) ? Z1i : Z2i;
            bf16* s = (wave == 0) ? sZr : sZi;
            const bf16* g = z + (size_t)(rowBase + srow) * FDIM + kloc + skc;
            #pragma unroll
            for (int t = 0; t < 4; ++t)
                gld_lds16(g + (size_t)t * 16 * FDIM, s + t * 512);
        } else if (wave == 2) {
            const bf16* g = Wt + (size_t)(colBase + srow) * 768 + kb + skc;
            #pragma unroll
            for (int t = 0; t < 4; ++t)
                gld_lds16(g + (size_t)t * 16 * 768, sW + t * 512);
        }
        __syncthreads();

        bf16x8 zr[2], zi[2], wv[2];
        #pragma unroll
        for (int m = 0; m < 2; ++m) {
            int r = wm * 32 + m * 16 + fr;
            zr[m] = *(const bf16x8*)&sZr[r * 32 + fk];
            zi[m] = *(const bf16x8*)&sZi[r * 32 + fk];
        }
        #pragma unroll
        for (int n = 0; n < 2; ++n) {
            int c = wn * 32 + n * 16 + fr;
            wv[n] = *(const bf16x8*)&sW[c * 32 + fk];
        }
        #pragma unroll
        for (int m = 0; m < 2; ++m)
            #pragma unroll
            for (int n = 0; n < 2; ++n) {
                accSr[m][n] = __builtin_amdgcn_mfma_f32_16x16x32_bf16(zr[m], wv[n], accSr[m][n], 0, 0, 0);
                accSi[m][n] = __builtin_amdgcn_mfma_f32_16x16x32_bf16(zi[m], wv[n], accSi[m][n], 0, 0, 0);
            }
        __syncthreads();
    }

    #pragma unroll
    for (int m = 0; m < 2; ++m)
        #pragma unroll
        for (int n = 0; n < 2; ++n) {
            int row0 = rowBase + wm * 32 + m * 16 + (lane >> 4) * 4;
            int col  = colBase + wn * 32 + n * 16 + (lane & 15);
            float bv = bias[col];
            #pragma unroll
            for (int r = 0; r < 4; ++r) {
                float vr = bv - accSi[m][n][r];
                float vi = bv + accSr[m][n][r];
                int row = row0 + r;
                size_t idx = (size_t)row * FDIM + col;
                if (O32r) {
                    O32r[idx] = vr; O32i[idx] = vi;
                }
                if (O16r_r) {
                    O16r_r[idx] = (bf16)vr; O16r_i[idx] = (bf16)vi;
                }
                if (OC) {
                    bf16x2 p; p[0] = (bf16)vr; p[1] = (bf16)vi;
                    ((bf16x2*)OC)[idx] = p;
                }
            }
        }
}

// ---------------------------------------------------------------------------
// 8. Head via MFMA + fused log_softmax.
//    FIX vs R6/R10: W staging needs 384 lane-writes (48 rows x 8 chunks);
//    with 256 threads the old `if (tid < 384)` single pass left rows 32..47
//    uninitialized -> NaN. Now two passes with idx = tid + e*256 < 384.
// ---------------------------------------------------------------------------
__global__ __launch_bounds__(256) void head_mfma(
    const bf16* __restrict__ Yrb,
    const bf16* __restrict__ Yib,
    const bf16* __restrict__ Wcb,
    const float* __restrict__ bc,
    float* __restrict__ out)          // [4096][40]
{
    __shared__ __align__(16) bf16 sY[64][72];
    __shared__ __align__(16) bf16 sW[48][72];
    __shared__ float sS[64][52];

    const int tid  = threadIdx.x;
    const int wave = tid >> 6;
    const int lane = tid & 63;
    const int r0 = blockIdx.x * 64;

    f32x4 acc[3] = {};

    for (int kb = 0; kb < 512; kb += 64) {
        const bf16* src = (kb < 256) ? Yrb : Yib;
        const int koff = kb & 255;
        #pragma unroll
        for (int e = 0; e < 2; ++e) {
            int idx = tid + e * 256;             // 0..511
            int rr = idx >> 3, kk = (idx & 7) * 8;
            *(bf16x8*)&sY[rr][kk] =
                *(const bf16x8*)&src[(size_t)(r0 + rr) * FDIM + koff + kk];
        }
        #pragma unroll
        for (int e = 0; e < 2; ++e) {
            int idx = tid + e * 256;             // 0..511; need 0..383
            if (idx < 384) {
                int rr = idx >> 3, kk = (idx & 7) * 8;
                *(bf16x8*)&sW[rr][kk] =
                    *(const bf16x8*)&Wcb[(size_t)rr * 512 + kb + kk];
            }
        }
        __syncthreads();
        #pragma unroll
        for (int ks = 0; ks < 2; ++ks) {
            bf16x8 a = *(const bf16x8*)&sY[wave * 16 + (lane & 15)][ks * 32 + (lane >> 4) * 8];
            #pragma unroll
            for (int n = 0; n < 3; ++n) {
                bf16x8 b = *(const bf16x8*)&sW[n * 16 + (lane & 15)][ks * 32 + (lane >> 4) * 8];
                acc[n] = __builtin_amdgcn_mfma_f32_16x16x32_bf16(a, b, acc[n], 0, 0, 0);
            }
        }
        __syncthreads();
    }

    // scatter S to LDS (C/D layout: col=lane&15, row=(lane>>4)*4+reg)
    #pragma unroll
    for (int n = 0; n < 3; ++n) {
        int col = n * 16 + (lane & 15);
        int rloc = wave * 16 + (lane >> 4) * 4;
        #pragma unroll
        for (int r = 0; r < 4; ++r)
            sS[rloc + r][col] = acc[n][r];
    }
    __syncthreads();

    if (tid < 64) {
        float mx = -INFINITY;
        #pragma unroll 8
        for (int c = 0; c < CDIM; ++c) {
            float lv = sS[tid][c] + bc[c];
            sS[tid][c] = lv;
            mx = fmaxf(mx, lv);
        }
        float se = 0.f;
        #pragma unroll 8
        for (int c = 0; c < CDIM; ++c) se += expf(sS[tid][c] - mx);
        float lse = mx + logf(se);
        #pragma unroll 8
        for (int c = 0; c < CDIM; ++c)
            out[(size_t)(r0 + tid) * CDIM + c] = sS[tid][c] - lse;
    }
}

// ---------------------------------------------------------------------------
// Launcher
// ---------------------------------------------------------------------------
extern "C" void kernel_launch(void* const* d_in, const int* in_sizes, int n_in,
                              void* d_out, int out_size, void* d_ws, size_t ws_size,
                              hipStream_t stream) {
    const float* real = (const float*)d_in[0];
    const float* imag = (const float*)d_in[1];
    const int*   edges = (const int*)d_in[2];
    const float* q    = (const float*)d_in[3];
    const float* ew   = (const float*)d_in[4];
    const float* W1   = (const float*)d_in[5];
    const float* b1   = (const float*)d_in[6];
    const float* W2   = (const float*)d_in[7];
    const float* b2   = (const float*)d_in[8];
    const float* Wc   = (const float*)d_in[9];
    const float* bc   = (const float*)d_in[10];
    float* out = (float*)d_out;

    // ---- workspace carve-up ----
    // Zeroed region (single memset): A, mask, cnt, rowsum, colsum, ent.
    char* w = (char*)d_ws;
    float*    A      = (float*)w;    w += NN * 4;                        // 64 MB
    unsigned* mask   = (unsigned*)w; w += (NN / 32) * sizeof(unsigned);  // 2 MB
    int*      cnt    = (int*)w;      w += N_NODES * 4;
    float*    rowsum = (float*)w;    w += N_NODES * 4;
    float*    colsum = (float*)w;    w += N_NODES * 4;
    Entry*    ent    = (Entry*)w;    w += (size_t)N_NODES * CAP * 16;    // 32 MB
    size_t zero_bytes = (size_t)((char*)w - (char*)d_ws);
    // Non-zeroed:
    int*   colidx = (int*)w; w += (size_t)N_NODES * CAP * 4;             // 8 MB
    float* dinv  = (float*)w; w += N_NODES * 4;
    bf16* Xr16 = (bf16*)w; w += NF * 2;
    bf16* Xi16 = (bf16*)w; w += NF * 2;
    bf16* XC   = (bf16*)w; w += NF * 4;                                  // interleaved
    bf16* Z1r  = (bf16*)w; w += NF * 2;
    bf16* Z1i  = (bf16*)w; w += NF * 2;
    bf16* Z1C  = (bf16*)w; w += NF * 4;
    bf16* Z2r  = (bf16*)w; w += NF * 2;
    bf16* Z2i  = (bf16*)w; w += NF * 2;
    float* Y1r32 = (float*)w; w += NF * 4;
    float* Y1i32 = (float*)w; w += NF * 4;
    bf16* Y1rb = (bf16*)w; w += NF * 2;
    bf16* Y1ib = (bf16*)w; w += NF * 2;
    bf16* Y1C  = (bf16*)w; w += NF * 4;
    bf16* Y2rb = (bf16*)w; w += NF * 2;
    bf16* Y2ib = (bf16*)w; w += NF * 2;
    bf16* W1t  = (bf16*)w; w += 256 * 768 * 2;
    bf16* W2t  = (bf16*)w; w += 256 * 768 * 2;
    bf16* Wcb  = (bf16*)w; w += 48 * 512 * 2;

    hipMemsetAsync(d_ws, 0, zero_bytes, stream);

    // ---- build sparse L (ELL) ----
    scatter_deg<<<(NEDGE + 255) / 256, 256, 0, stream>>>(edges, ew, A, rowsum, colsum);
    dinv_k<<<16, 256, 0, stream>>>(rowsum, colsum, dinv);
    build_cells<<<(2 * NEDGE + 255) / 256, 256, 0, stream>>>(edges, mask, colidx, cnt);
    fill_ell<<<(N_NODES * CAP) / 256, 256, 0, stream>>>(colidx, cnt, A, dinv, q, ent);

    // ---- casts ----
    cast_in2<<<NF / 256, 256, 0, stream>>>(real, imag, Xr16, Xi16, XC);
    cast_w<<<768, 256, 0, stream>>>(W1, W1t);
    cast_w<<<768, 256, 0, stream>>>(W2, W2t);
    cast_wc<<<96, 256, 0, stream>>>(Wc, Wcb);

    dim3 gW(FDIM / 64, N_NODES / 64);   // (4, 64)

    // ---- Layer 1 ----
    spmm_k<<<N_NODES, 256, 0, stream>>>(cnt, ent, XC, nullptr,
                                        1.f, 0.f, Z1r, Z1i, Z1C);
    spmm_k<<<N_NODES, 256, 0, stream>>>(cnt, ent, Z1C, XC,
                                        2.f, -1.f, Z2r, Z2i, nullptr);
    wapply_mfma<<<gW, 256, 0, stream>>>(Xr16, Xi16, Z1r, Z1i, Z2r, Z2i,
                                        W1t, b1,
                                        Y1r32, Y1i32,
                                        Y1rb, Y1ib,
                                        Y1C);

    // ---- Layer 2 ----
    spmm_k<<<N_NODES, 256, 0, stream>>>(cnt, ent, Y1C, nullptr,
                                        1.f, 0.f, Z1r, Z1i, Z1C);
    spmm_k<<<N_NODES, 256, 0, stream>>>(cnt, ent, Z1C, Y1C,
                                        2.f, -1.f, Z2r, Z2i, nullptr);
    wapply_mfma<<<gW, 256, 0, stream>>>(Y1rb, Y1ib, Z1r, Z1i, Z2r, Z2i,
                                        W2t, b2,
                                        nullptr, nullptr,
                                        Y2rb, Y2ib,
                                        nullptr);

    // ---- Head (MFMA, staging fixed) ----
    head_mfma<<<64, 256, 0, stream>>>(Y2rb, Y2ib, Wcb, bc, out);
}

// Round 12
// 279.765 us; speedup vs baseline: 1.9812x; 1.0870x over previous
//
#include <hip/hip_runtime.h>
#include <cmath>

#define N_NODES 4096
#define FDIM    256
#define CDIM    40
#define NEDGE   131072
#define CAP     256                  // ELL row capacity (row nnz ~Poisson(64))
#define HBITS   20
#define HSIZE   (1 << HBITS)         // 1M hash slots, load <= 0.125
#define TWO_PI_F 6.28318530717958647692f

typedef __bf16 bf16;
typedef __bf16 bf16x2 __attribute__((ext_vector_type(2)));
typedef __bf16 bf16x4 __attribute__((ext_vector_type(4)));
typedef __bf16 bf16x8 __attribute__((ext_vector_type(8)));
typedef float  f32x4  __attribute__((ext_vector_type(4)));

static constexpr size_t NF = (size_t)N_NODES * FDIM;      // 1,048,576

struct __align__(16) Entry { float lr, li; int col, pad; };

// async global->LDS, 16B per lane, dest = ldsBase + lane*16
__device__ __forceinline__ void gld_lds16(const bf16* g, bf16* s) {
    __builtin_amdgcn_global_load_lds(
        (const __attribute__((address_space(1))) void*)g,
        (__attribute__((address_space(3))) void*)s,
        16, 0, 0);
}

__device__ __forceinline__ unsigned cell_hash(unsigned cell) {
    return (cell * 2654435761u) >> (32 - HBITS);
}

// ---------------------------------------------------------------------------
// 1. Hash-insert edges (duplicate weights summed) + raw row/col degree sums.
//    hkey/hval/rowsum/colsum pre-zeroed. Empty slot: key==0; stored key=cell+1.
// ---------------------------------------------------------------------------
__global__ void hash_insert(const int* __restrict__ edges,
                            const float* __restrict__ ew,
                            int* __restrict__ hkey, float* __restrict__ hval,
                            float* __restrict__ rowsum, float* __restrict__ colsum) {
    int e = blockIdx.x * blockDim.x + threadIdx.x;
    if (e >= NEDGE) return;
    int r = edges[e], c = edges[NEDGE + e];
    float wv = ew[e];
    atomicAdd(rowsum + r, wv);
    atomicAdd(colsum + c, wv);
    unsigned cell = (unsigned)r * N_NODES + c;      // < 2^24
    unsigned h = cell_hash(cell);
    for (;;) {
        int old = atomicCAS(hkey + h, 0, (int)(cell + 1));
        if (old == 0 || old == (int)(cell + 1)) { atomicAdd(hval + h, wv); break; }
        h = (h + 1) & (HSIZE - 1);
    }
}

// 2. dinv = (0.5*(rowsum+colsum))^-0.5 with 0 -> 1
__global__ void dinv_k(const float* __restrict__ rowsum,
                       const float* __restrict__ colsum,
                       float* __restrict__ dinv) {
    int j = blockIdx.x * blockDim.x + threadIdx.x;
    if (j < N_NODES) {
        float d = 0.5f * (rowsum[j] + colsum[j]);
        if (d == 0.f) d = 1.f;
        dinv[j] = 1.0f / sqrtf(d);
    }
}

// ---------------------------------------------------------------------------
// 3. Hash -> ELL. For each occupied slot (i,j): a = val, b = mirror lookup.
//    Entry(i,j) written; if mirror absent (and i!=j) the conjugate Entry(j,i)
//    is also emitted (a'=0, b'=a -> an'=an, theta'=-theta). Every ent slot
//    spmm reads (pos < min(cnt,CAP)) is written here by construction.
//    cnt pre-zeroed.
// ---------------------------------------------------------------------------
__global__ __launch_bounds__(256) void hash_to_ell(
    const int* __restrict__ hkey, const float* __restrict__ hval,
    const float* __restrict__ dinv, const float* __restrict__ qptr,
    int* __restrict__ cnt, Entry* __restrict__ ent) {
    int h = blockIdx.x * 256 + threadIdx.x;
    int k = hkey[h];
    if (k == 0) return;
    unsigned cell = (unsigned)(k - 1);
    int i = cell >> 12, j = cell & 4095;
    float a = hval[h];
    float b = 0.f;
    bool mirror = false;
    if (i == j) { b = a; mirror = true; }
    else {
        unsigned mcell = (unsigned)j * N_NODES + i;
        unsigned hh = cell_hash(mcell);
        for (;;) {
            int kk = hkey[hh];
            if (kk == (int)(mcell + 1)) { b = hval[hh]; mirror = true; break; }
            if (kk == 0) break;
            hh = (hh + 1) & (HSIZE - 1);
        }
    }
    float an = 0.5f * (a + b) * dinv[i] * dinv[j];
    float s, c;
    sincosf(TWO_PI_F * qptr[0] * (a - b), &s, &c);
    int pos = atomicAdd(cnt + i, 1);
    if (pos < CAP) {
        Entry en; en.lr = -an * c; en.li = an * s; en.col = j; en.pad = 0;
        ent[(size_t)i * CAP + pos] = en;
    }
    if (!mirror) {   // emit conjugate cell (j,i)
        int pos2 = atomicAdd(cnt + j, 1);
        if (pos2 < CAP) {
            Entry en; en.lr = -an * c; en.li = -an * s; en.col = i; en.pad = 0;
            ent[(size_t)j * CAP + pos2] = en;
        }
    }
}

// ---------------------------------------------------------------------------
// 4. Cast X -> planar bf16 (wapply input) + interleaved bf16 (spmm input)
// ---------------------------------------------------------------------------
__global__ __launch_bounds__(256) void cast_in2(const float* __restrict__ Xr,
                                                const float* __restrict__ Xi,
                                                bf16* __restrict__ Xr16,
                                                bf16* __restrict__ Xi16,
                                                bf16* __restrict__ XC) {
    int idx = blockIdx.x * 256 + threadIdx.x;     // n*256+f
    float vr = Xr[idx], vi = Xi[idx];
    Xr16[idx] = (bf16)vr; Xi16[idx] = (bf16)vi;
    bf16x2 p; p[0] = (bf16)vr; p[1] = (bf16)vi;
    ((bf16x2*)XC)[idx] = p;
}

// cast W [3][256][256] -> Wt bf16 [256][768], Wt[n][o*256+k] = W[o][k][n]
__global__ __launch_bounds__(256) void cast_w(const float* __restrict__ W,
                                              bf16* __restrict__ Wt) {
    int idx = blockIdx.x * 256 + threadIdx.x;
    if (idx < 256 * 768) {
        int nout = idx / 768, kk = idx - nout * 768;
        int o = kk >> 8, k = kk & 255;
        Wt[idx] = (bf16)W[((size_t)o * 256 + k) * 256 + nout];
    }
}

// cast Wc [40][512] -> bf16 [48][512], rows 40..47 zero
__global__ __launch_bounds__(256) void cast_wc(const float* __restrict__ Wc,
                                               bf16* __restrict__ Wcb) {
    int idx = blockIdx.x * 256 + threadIdx.x;     // < 48*512
    int row = idx >> 9, k = idx & 511;
    Wcb[idx] = (row < CDIM) ? (bf16)Wc[row * 512 + k] : (bf16)0.f;
}

// ---------------------------------------------------------------------------
// 5. Sparse complex SpMM (ELL), one block (4 waves) per row. (R8-proven.)
// ---------------------------------------------------------------------------
__global__ __launch_bounds__(256) void spmm_k(
    const int* __restrict__ cnt, const Entry* __restrict__ ent,
    const bf16* __restrict__ XC,
    const bf16* __restrict__ C0C,
    float alpha, float beta,
    bf16* __restrict__ Zr, bf16* __restrict__ Zi, bf16* __restrict__ ZC)
{
    __shared__ f32x4 redR[3][64];
    __shared__ f32x4 redI[3][64];

    const int wave = threadIdx.x >> 6, lane = threadIdx.x & 63;
    const int row = blockIdx.x;
    int n1 = cnt[row]; if (n1 > CAP) n1 = CAP;
    const Entry* erow = ent + (size_t)row * CAP;

    float ar[4] = {}, ai[4] = {};
    int e = wave;
    for (; e + 4 < n1; e += 8) {
        Entry e0 = erow[e];
        Entry e1 = erow[e + 4];
        bf16x8 x0 = *(const bf16x8*)&XC[(size_t)(e0.col & 4095) * 512 + lane * 8];
        bf16x8 x1 = *(const bf16x8*)&XC[(size_t)(e1.col & 4095) * 512 + lane * 8];
        #pragma unroll
        for (int c = 0; c < 4; ++c) {
            float xr0 = (float)x0[2 * c], xi0 = (float)x0[2 * c + 1];
            ar[c] += e0.lr * xr0 - e0.li * xi0;
            ai[c] += e0.lr * xi0 + e0.li * xr0;
            float xr1 = (float)x1[2 * c], xi1 = (float)x1[2 * c + 1];
            ar[c] += e1.lr * xr1 - e1.li * xi1;
            ai[c] += e1.lr * xi1 + e1.li * xr1;
        }
    }
    if (e < n1) {
        Entry e0 = erow[e];
        bf16x8 x0 = *(const bf16x8*)&XC[(size_t)(e0.col & 4095) * 512 + lane * 8];
        #pragma unroll
        for (int c = 0; c < 4; ++c) {
            float xr0 = (float)x0[2 * c], xi0 = (float)x0[2 * c + 1];
            ar[c] += e0.lr * xr0 - e0.li * xi0;
            ai[c] += e0.lr * xi0 + e0.li * xr0;
        }
    }

    if (wave != 0) {
        f32x4 r, i;
        #pragma unroll
        for (int c = 0; c < 4; ++c) { r[c] = ar[c]; i[c] = ai[c]; }
        redR[wave - 1][lane] = r;
        redI[wave - 1][lane] = i;
    }
    __syncthreads();
    if (wave != 0) return;

    #pragma unroll
    for (int w = 0; w < 3; ++w) {
        f32x4 r = redR[w][lane], i = redI[w][lane];
        #pragma unroll
        for (int c = 0; c < 4; ++c) { ar[c] += r[c]; ai[c] += i[c]; }
    }

    float vr[4], vi[4];
    if (beta != 0.f) {
        bf16x8 c0 = *(const bf16x8*)&C0C[(size_t)row * 512 + lane * 8];
        #pragma unroll
        for (int c = 0; c < 4; ++c) {
            vr[c] = alpha * ar[c] + beta * (float)c0[2 * c];
            vi[c] = alpha * ai[c] + beta * (float)c0[2 * c + 1];
        }
    } else {
        #pragma unroll
        for (int c = 0; c < 4; ++c) { vr[c] = alpha * ar[c]; vi[c] = alpha * ai[c]; }
    }
    size_t base = (size_t)row * FDIM + lane * 4;
    bf16x4 pr, pi;
    #pragma unroll
    for (int c = 0; c < 4; ++c) { pr[c] = (bf16)vr[c]; pi[c] = (bf16)vi[c]; }
    *(bf16x4*)&Zr[base] = pr;
    *(bf16x4*)&Zi[base] = pi;
    if (ZC) {
        bf16x8 o;
        #pragma unroll
        for (int c = 0; c < 4; ++c) { o[2 * c] = pr[c]; o[2 * c + 1] = pi[c]; }
        *(bf16x8*)&ZC[(size_t)row * 512 + lane * 8] = o;
    }
}

// ---------------------------------------------------------------------------
// 6. wapply via MFMA (R3/R7/R9-validated, byte-identical).
// ---------------------------------------------------------------------------
__global__ __launch_bounds__(256) void wapply_mfma(
    const bf16* __restrict__ Z0r, const bf16* __restrict__ Z0i,
    const bf16* __restrict__ Z1r, const bf16* __restrict__ Z1i,
    const bf16* __restrict__ Z2r, const bf16* __restrict__ Z2i,
    const bf16* __restrict__ Wt,      // [256][768]
    const float* __restrict__ bias,   // [256]
    float* __restrict__ O32r, float* __restrict__ O32i,
    bf16* __restrict__ O16r_r, bf16* __restrict__ O16r_i,
    bf16* __restrict__ OC)
{
    __shared__ __align__(16) bf16 sZr[64 * 32];
    __shared__ __align__(16) bf16 sZi[64 * 32];
    __shared__ __align__(16) bf16 sW [64 * 32];

    const int tid  = threadIdx.x;
    const int wave = tid >> 6;
    const int lane = tid & 63;
    const int rowBase = blockIdx.y * 64;
    const int colBase = blockIdx.x * 64;

    const int srow = lane >> 2;
    const int skc  = (lane & 3) * 8;

    f32x4 accSr[2][2] = {}, accSi[2][2] = {};
    const int wm = wave & 1, wn = wave >> 1;
    const int fr = lane & 15;
    const int fk = (lane >> 4) * 8;

    for (int kb = 0; kb < 3 * FDIM; kb += 32) {
        int order = kb >> 8;
        int kloc  = kb & 255;
        if (wave == 0 || wave == 1) {
            const bf16* z;
            if (wave == 0) z = (order == 0) ? Z0r : (order == 1) ? Z1r : Z2r;
            else           z = (order == 0) ? Z0i : (order == 1) ? Z1i : Z2i;
            bf16* s = (wave == 0) ? sZr : sZi;
            const bf16* g = z + (size_t)(rowBase + srow) * FDIM + kloc + skc;
            #pragma unroll
            for (int t = 0; t < 4; ++t)
                gld_lds16(g + (size_t)t * 16 * FDIM, s + t * 512);
        } else if (wave == 2) {
            const bf16* g = Wt + (size_t)(colBase + srow) * 768 + kb + skc;
            #pragma unroll
            for (int t = 0; t < 4; ++t)
                gld_lds16(g + (size_t)t * 16 * 768, sW + t * 512);
        }
        __syncthreads();

        bf16x8 zr[2], zi[2], wv[2];
        #pragma unroll
        for (int m = 0; m < 2; ++m) {
            int r = wm * 32 + m * 16 + fr;
            zr[m] = *(const bf16x8*)&sZr[r * 32 + fk];
            zi[m] = *(const bf16x8*)&sZi[r * 32 + fk];
        }
        #pragma unroll
        for (int n = 0; n < 2; ++n) {
            int c = wn * 32 + n * 16 + fr;
            wv[n] = *(const bf16x8*)&sW[c * 32 + fk];
        }
        #pragma unroll
        for (int m = 0; m < 2; ++m)
            #pragma unroll
            for (int n = 0; n < 2; ++n) {
                accSr[m][n] = __builtin_amdgcn_mfma_f32_16x16x32_bf16(zr[m], wv[n], accSr[m][n], 0, 0, 0);
                accSi[m][n] = __builtin_amdgcn_mfma_f32_16x16x32_bf16(zi[m], wv[n], accSi[m][n], 0, 0, 0);
            }
        __syncthreads();
    }

    #pragma unroll
    for (int m = 0; m < 2; ++m)
        #pragma unroll
        for (int n = 0; n < 2; ++n) {
            int row0 = rowBase + wm * 32 + m * 16 + (lane >> 4) * 4;
            int col  = colBase + wn * 32 + n * 16 + (lane & 15);
            float bv = bias[col];
            #pragma unroll
            for (int r = 0; r < 4; ++r) {
                float vr = bv - accSi[m][n][r];
                float vi = bv + accSr[m][n][r];
                int row = row0 + r;
                size_t idx = (size_t)row * FDIM + col;
                if (O32r) {
                    O32r[idx] = vr; O32i[idx] = vi;
                }
                if (O16r_r) {
                    O16r_r[idx] = (bf16)vr; O16r_i[idx] = (bf16)vi;
                }
                if (OC) {
                    bf16x2 p; p[0] = (bf16)vr; p[1] = (bf16)vi;
                    ((bf16x2*)OC)[idx] = p;
                }
            }
        }
}

// ---------------------------------------------------------------------------
// 7. Head via MFMA + fused log_softmax (R11-validated: W staged in two
//    guarded passes, idx = tid + e*256 < 384).
// ---------------------------------------------------------------------------
__global__ __launch_bounds__(256) void head_mfma(
    const bf16* __restrict__ Yrb,
    const bf16* __restrict__ Yib,
    const bf16* __restrict__ Wcb,
    const float* __restrict__ bc,
    float* __restrict__ out)          // [4096][40]
{
    __shared__ __align__(16) bf16 sY[64][72];
    __shared__ __align__(16) bf16 sW[48][72];
    __shared__ float sS[64][52];

    const int tid  = threadIdx.x;
    const int wave = tid >> 6;
    const int lane = tid & 63;
    const int r0 = blockIdx.x * 64;

    f32x4 acc[3] = {};

    for (int kb = 0; kb < 512; kb += 64) {
        const bf16* src = (kb < 256) ? Yrb : Yib;
        const int koff = kb & 255;
        #pragma unroll
        for (int e = 0; e < 2; ++e) {
            int idx = tid + e * 256;             // 0..511
            int rr = idx >> 3, kk = (idx & 7) * 8;
            *(bf16x8*)&sY[rr][kk] =
                *(const bf16x8*)&src[(size_t)(r0 + rr) * FDIM + koff + kk];
        }
        #pragma unroll
        for (int e = 0; e < 2; ++e) {
            int idx = tid + e * 256;             // need 0..383
            if (idx < 384) {
                int rr = idx >> 3, kk = (idx & 7) * 8;
                *(bf16x8*)&sW[rr][kk] =
                    *(const bf16x8*)&Wcb[(size_t)rr * 512 + kb + kk];
            }
        }
        __syncthreads();
        #pragma unroll
        for (int ks = 0; ks < 2; ++ks) {
            bf16x8 a = *(const bf16x8*)&sY[wave * 16 + (lane & 15)][ks * 32 + (lane >> 4) * 8];
            #pragma unroll
            for (int n = 0; n < 3; ++n) {
                bf16x8 b = *(const bf16x8*)&sW[n * 16 + (lane & 15)][ks * 32 + (lane >> 4) * 8];
                acc[n] = __builtin_amdgcn_mfma_f32_16x16x32_bf16(a, b, acc[n], 0, 0, 0);
            }
        }
        __syncthreads();
    }

    #pragma unroll
    for (int n = 0; n < 3; ++n) {
        int col = n * 16 + (lane & 15);
        int rloc = wave * 16 + (lane >> 4) * 4;
        #pragma unroll
        for (int r = 0; r < 4; ++r)
            sS[rloc + r][col] = acc[n][r];
    }
    __syncthreads();

    if (tid < 64) {
        float mx = -INFINITY;
        #pragma unroll 8
        for (int c = 0; c < CDIM; ++c) {
            float lv = sS[tid][c] + bc[c];
            sS[tid][c] = lv;
            mx = fmaxf(mx, lv);
        }
        float se = 0.f;
        #pragma unroll 8
        for (int c = 0; c < CDIM; ++c) se += expf(sS[tid][c] - mx);
        float lse = mx + logf(se);
        #pragma unroll 8
        for (int c = 0; c < CDIM; ++c)
            out[(size_t)(r0 + tid) * CDIM + c] = sS[tid][c] - lse;
    }
}

// ---------------------------------------------------------------------------
// Launcher
// ---------------------------------------------------------------------------
extern "C" void kernel_launch(void* const* d_in, const int* in_sizes, int n_in,
                              void* d_out, int out_size, void* d_ws, size_t ws_size,
                              hipStream_t stream) {
    const float* real = (const float*)d_in[0];
    const float* imag = (const float*)d_in[1];
    const int*   edges = (const int*)d_in[2];
    const float* q    = (const float*)d_in[3];
    const float* ew   = (const float*)d_in[4];
    const float* W1   = (const float*)d_in[5];
    const float* b1   = (const float*)d_in[6];
    const float* W2   = (const float*)d_in[7];
    const float* b2   = (const float*)d_in[8];
    const float* Wc   = (const float*)d_in[9];
    const float* bc   = (const float*)d_in[10];
    float* out = (float*)d_out;

    // ---- workspace carve-up ----
    // Zeroed region (single memset, ~8 MB): hkey, hval, cnt, rowsum, colsum.
    char* w = (char*)d_ws;
    int*      hkey   = (int*)w;   w += (size_t)HSIZE * 4;       // 4 MB
    float*    hval   = (float*)w; w += (size_t)HSIZE * 4;       // 4 MB
    int*      cnt    = (int*)w;   w += N_NODES * 4;
    float*    rowsum = (float*)w; w += N_NODES * 4;
    float*    colsum = (float*)w; w += N_NODES * 4;
    size_t zero_bytes = (size_t)((char*)w - (char*)d_ws);
    // Non-zeroed:
    Entry* ent  = (Entry*)w; w += (size_t)N_NODES * CAP * 16;   // 16 MB
    float* dinv = (float*)w; w += N_NODES * 4;
    bf16* Xr16 = (bf16*)w; w += NF * 2;
    bf16* Xi16 = (bf16*)w; w += NF * 2;
    bf16* XC   = (bf16*)w; w += NF * 4;                         // interleaved
    bf16* Z1r  = (bf16*)w; w += NF * 2;
    bf16* Z1i  = (bf16*)w; w += NF * 2;
    bf16* Z1C  = (bf16*)w; w += NF * 4;
    bf16* Z2r  = (bf16*)w; w += NF * 2;
    bf16* Z2i  = (bf16*)w; w += NF * 2;
    float* Y1r32 = (float*)w; w += NF * 4;
    float* Y1i32 = (float*)w; w += NF * 4;
    bf16* Y1rb = (bf16*)w; w += NF * 2;
    bf16* Y1ib = (bf16*)w; w += NF * 2;
    bf16* Y1C  = (bf16*)w; w += NF * 4;
    bf16* Y2rb = (bf16*)w; w += NF * 2;
    bf16* Y2ib = (bf16*)w; w += NF * 2;
    bf16* W1t  = (bf16*)w; w += 256 * 768 * 2;
    bf16* W2t  = (bf16*)w; w += 256 * 768 * 2;
    bf16* Wcb  = (bf16*)w; w += 48 * 512 * 2;

    hipMemsetAsync(d_ws, 0, zero_bytes, stream);

    // ---- build sparse L (hash -> ELL) ----
    hash_insert<<<(NEDGE + 255) / 256, 256, 0, stream>>>(edges, ew, hkey, hval,
                                                         rowsum, colsum);
    dinv_k<<<16, 256, 0, stream>>>(rowsum, colsum, dinv);
    hash_to_ell<<<HSIZE / 256, 256, 0, stream>>>(hkey, hval, dinv, q, cnt, ent);

    // ---- casts ----
    cast_in2<<<NF / 256, 256, 0, stream>>>(real, imag, Xr16, Xi16, XC);
    cast_w<<<768, 256, 0, stream>>>(W1, W1t);
    cast_w<<<768, 256, 0, stream>>>(W2, W2t);
    cast_wc<<<96, 256, 0, stream>>>(Wc, Wcb);

    dim3 gW(FDIM / 64, N_NODES / 64);   // (4, 64)

    // ---- Layer 1 ----
    spmm_k<<<N_NODES, 256, 0, stream>>>(cnt, ent, XC, nullptr,
                                        1.f, 0.f, Z1r, Z1i, Z1C);
    spmm_k<<<N_NODES, 256, 0, stream>>>(cnt, ent, Z1C, XC,
                                        2.f, -1.f, Z2r, Z2i, nullptr);
    wapply_mfma<<<gW, 256, 0, stream>>>(Xr16, Xi16, Z1r, Z1i, Z2r, Z2i,
                                        W1t, b1,
                                        Y1r32, Y1i32,
                                        Y1rb, Y1ib,
                                        Y1C);

    // ---- Layer 2 ----
    spmm_k<<<N_NODES, 256, 0, stream>>>(cnt, ent, Y1C, nullptr,
                                        1.f, 0.f, Z1r, Z1i, Z1C);
    spmm_k<<<N_NODES, 256, 0, stream>>>(cnt, ent, Z1C, Y1C,
                                        2.f, -1.f, Z2r, Z2i, nullptr);
    wapply_mfma<<<gW, 256, 0, stream>>>(Y1rb, Y1ib, Z1r, Z1i, Z2r, Z2i,
                                        W2t, b2,
                                        nullptr, nullptr,
                                        Y2rb, Y2ib,
                                        nullptr);

    // ---- Head ----
    head_mfma<<<64, 256, 0, stream>>>(Y2rb, Y2ib, Wcb, bc, out);
}

// Round 13
// 272.741 us; speedup vs baseline: 2.0322x; 1.0258x over previous
//
#include <hip/hip_runtime.h>
#include <cmath>

#define N_NODES 4096
#define FDIM    256
#define CDIM    40
#define NEDGE   131072
#define CAP     256                  // ELL row capacity (row nnz ~Poisson(64))
#define HBITS   20
#define HSIZE   (1 << HBITS)         // 1M hash slots, load <= 0.125
#define TWO_PI_F 6.28318530717958647692f

typedef __bf16 bf16;
typedef __bf16 bf16x2 __attribute__((ext_vector_type(2)));
typedef __bf16 bf16x4 __attribute__((ext_vector_type(4)));
typedef __bf16 bf16x8 __attribute__((ext_vector_type(8)));
typedef float  f32x4  __attribute__((ext_vector_type(4)));

static constexpr size_t NF = (size_t)N_NODES * FDIM;      // 1,048,576

struct __align__(16) Entry { float lr, li; int col, pad; };

// async global->LDS, 16B per lane, dest = ldsBase + lane*16
__device__ __forceinline__ void gld_lds16(const bf16* g, bf16* s) {
    __builtin_amdgcn_global_load_lds(
        (const __attribute__((address_space(1))) void*)g,
        (__attribute__((address_space(3))) void*)s,
        16, 0, 0);
}

__device__ __forceinline__ unsigned cell_hash(unsigned cell) {
    return (cell * 2654435761u) >> (32 - HBITS);
}

// ---------------------------------------------------------------------------
// 1. Hash-insert edges (duplicate weights summed) + raw row/col degree sums.
//    hkey/hval/rowsum/colsum pre-zeroed. Empty slot: key==0; stored key=cell+1.
// ---------------------------------------------------------------------------
__global__ void hash_insert(const int* __restrict__ edges,
                            const float* __restrict__ ew,
                            int* __restrict__ hkey, float* __restrict__ hval,
                            float* __restrict__ rowsum, float* __restrict__ colsum) {
    int e = blockIdx.x * blockDim.x + threadIdx.x;
    if (e >= NEDGE) return;
    int r = edges[e], c = edges[NEDGE + e];
    float wv = ew[e];
    atomicAdd(rowsum + r, wv);
    atomicAdd(colsum + c, wv);
    unsigned cell = (unsigned)r * N_NODES + c;      // < 2^24
    unsigned h = cell_hash(cell);
    for (;;) {
        int old = atomicCAS(hkey + h, 0, (int)(cell + 1));
        if (old == 0 || old == (int)(cell + 1)) { atomicAdd(hval + h, wv); break; }
        h = (h + 1) & (HSIZE - 1);
    }
}

// ---------------------------------------------------------------------------
// 2. Hash -> ELL, dinv inlined from rowsum/colsum (deletes dinv_k dispatch).
//    For each occupied slot (i,j): a = val, b = mirror lookup. Entry(i,j)
//    written; if mirror absent (and i!=j) the conjugate Entry(j,i) is also
//    emitted (an'=an, theta'=-theta). Every ent slot spmm reads
//    (pos < min(cnt,CAP)) is written here by construction. cnt pre-zeroed.
// ---------------------------------------------------------------------------
__global__ __launch_bounds__(256) void hash_to_ell(
    const int* __restrict__ hkey, const float* __restrict__ hval,
    const float* __restrict__ rowsum, const float* __restrict__ colsum,
    const float* __restrict__ qptr,
    int* __restrict__ cnt, Entry* __restrict__ ent) {
    int h = blockIdx.x * 256 + threadIdx.x;
    int k = hkey[h];
    if (k == 0) return;
    unsigned cell = (unsigned)(k - 1);
    int i = cell >> 12, j = cell & 4095;
    float a = hval[h];
    float b = 0.f;
    bool mirror = false;
    if (i == j) { b = a; mirror = true; }
    else {
        unsigned mcell = (unsigned)j * N_NODES + i;
        unsigned hh = cell_hash(mcell);
        for (;;) {
            int kk = hkey[hh];
            if (kk == (int)(mcell + 1)) { b = hval[hh]; mirror = true; break; }
            if (kk == 0) break;
            hh = (hh + 1) & (HSIZE - 1);
        }
    }
    float di = 0.5f * (rowsum[i] + colsum[i]); if (di == 0.f) di = 1.f;
    float dj = 0.5f * (rowsum[j] + colsum[j]); if (dj == 0.f) dj = 1.f;
    float an = 0.5f * (a + b) / sqrtf(di * dj);
    float s, c;
    sincosf(TWO_PI_F * qptr[0] * (a - b), &s, &c);
    int pos = atomicAdd(cnt + i, 1);
    if (pos < CAP) {
        Entry en; en.lr = -an * c; en.li = an * s; en.col = j; en.pad = 0;
        ent[(size_t)i * CAP + pos] = en;
    }
    if (!mirror) {   // emit conjugate cell (j,i)
        int pos2 = atomicAdd(cnt + j, 1);
        if (pos2 < CAP) {
            Entry en; en.lr = -an * c; en.li = -an * s; en.col = i; en.pad = 0;
            ent[(size_t)j * CAP + pos2] = en;
        }
    }
}

// ---------------------------------------------------------------------------
// 3. Cast X -> planar bf16 (wapply input) + interleaved bf16 (spmm input)
// ---------------------------------------------------------------------------
__global__ __launch_bounds__(256) void cast_in2(const float* __restrict__ Xr,
                                                const float* __restrict__ Xi,
                                                bf16* __restrict__ Xr16,
                                                bf16* __restrict__ Xi16,
                                                bf16* __restrict__ XC) {
    int idx = blockIdx.x * 256 + threadIdx.x;     // n*256+f
    float vr = Xr[idx], vi = Xi[idx];
    Xr16[idx] = (bf16)vr; Xi16[idx] = (bf16)vi;
    bf16x2 p; p[0] = (bf16)vr; p[1] = (bf16)vi;
    ((bf16x2*)XC)[idx] = p;
}

// ---------------------------------------------------------------------------
// 4. Fused weight casts: W1->W1t, W2->W2t ([256][768], Wt[n][o*256+k] =
//    W[o][k][n]) and Wc [40][512] -> Wcb [48][512] (rows 40..47 zero).
// ---------------------------------------------------------------------------
#define NWT (256 * 768)
__global__ __launch_bounds__(256) void cast_weights(
    const float* __restrict__ W1, const float* __restrict__ W2,
    const float* __restrict__ Wc,
    bf16* __restrict__ W1t, bf16* __restrict__ W2t, bf16* __restrict__ Wcb) {
    int idx = blockIdx.x * 256 + threadIdx.x;
    if (idx < 2 * NWT) {
        const float* W = (idx < NWT) ? W1 : W2;
        bf16* Wt = (idx < NWT) ? W1t : W2t;
        int id = (idx < NWT) ? idx : idx - NWT;
        int nout = id / 768, kk = id - nout * 768;
        int o = kk >> 8, k = kk & 255;
        Wt[id] = (bf16)W[((size_t)o * 256 + k) * 256 + nout];
    } else {
        int id = idx - 2 * NWT;
        if (id < 48 * 512) {
            int row = id >> 9, k = id & 511;
            Wcb[id] = (row < CDIM) ? (bf16)Wc[row * 512 + k] : (bf16)0.f;
        }
    }
}

// ---------------------------------------------------------------------------
// 5. Sparse complex SpMM (ELL), v3: one block (4 waves) per row, entries
//    wave-strided, unroll-by-4 -> 4 outstanding XC gathers per wave.
// ---------------------------------------------------------------------------
__global__ __launch_bounds__(256) void spmm_k(
    const int* __restrict__ cnt, const Entry* __restrict__ ent,
    const bf16* __restrict__ XC,
    const bf16* __restrict__ C0C,
    float alpha, float beta,
    bf16* __restrict__ Zr, bf16* __restrict__ Zi, bf16* __restrict__ ZC)
{
    __shared__ f32x4 redR[3][64];
    __shared__ f32x4 redI[3][64];

    const int wave = threadIdx.x >> 6, lane = threadIdx.x & 63;
    const int row = blockIdx.x;
    int n1 = cnt[row]; if (n1 > CAP) n1 = CAP;
    const Entry* erow = ent + (size_t)row * CAP;

    float ar[4] = {}, ai[4] = {};
    int e = wave;
    // 4 independent XC gathers in flight (entries e, e+4, e+8, e+12)
    for (; e + 12 < n1; e += 16) {
        Entry e0 = erow[e];
        Entry e1 = erow[e + 4];
        Entry e2 = erow[e + 8];
        Entry e3 = erow[e + 12];
        bf16x8 x0 = *(const bf16x8*)&XC[(size_t)(e0.col & 4095) * 512 + lane * 8];
        bf16x8 x1 = *(const bf16x8*)&XC[(size_t)(e1.col & 4095) * 512 + lane * 8];
        bf16x8 x2 = *(const bf16x8*)&XC[(size_t)(e2.col & 4095) * 512 + lane * 8];
        bf16x8 x3 = *(const bf16x8*)&XC[(size_t)(e3.col & 4095) * 512 + lane * 8];
        #pragma unroll
        for (int c = 0; c < 4; ++c) {
            float xr, xi;
            xr = (float)x0[2 * c]; xi = (float)x0[2 * c + 1];
            ar[c] += e0.lr * xr - e0.li * xi;  ai[c] += e0.lr * xi + e0.li * xr;
            xr = (float)x1[2 * c]; xi = (float)x1[2 * c + 1];
            ar[c] += e1.lr * xr - e1.li * xi;  ai[c] += e1.lr * xi + e1.li * xr;
            xr = (float)x2[2 * c]; xi = (float)x2[2 * c + 1];
            ar[c] += e2.lr * xr - e2.li * xi;  ai[c] += e2.lr * xi + e2.li * xr;
            xr = (float)x3[2 * c]; xi = (float)x3[2 * c + 1];
            ar[c] += e3.lr * xr - e3.li * xi;  ai[c] += e3.lr * xi + e3.li * xr;
        }
    }
    for (; e < n1; e += 4) {
        Entry e0 = erow[e];
        bf16x8 x0 = *(const bf16x8*)&XC[(size_t)(e0.col & 4095) * 512 + lane * 8];
        #pragma unroll
        for (int c = 0; c < 4; ++c) {
            float xr0 = (float)x0[2 * c], xi0 = (float)x0[2 * c + 1];
            ar[c] += e0.lr * xr0 - e0.li * xi0;
            ai[c] += e0.lr * xi0 + e0.li * xr0;
        }
    }

    if (wave != 0) {
        f32x4 r, i;
        #pragma unroll
        for (int c = 0; c < 4; ++c) { r[c] = ar[c]; i[c] = ai[c]; }
        redR[wave - 1][lane] = r;
        redI[wave - 1][lane] = i;
    }
    __syncthreads();
    if (wave != 0) return;

    #pragma unroll
    for (int w = 0; w < 3; ++w) {
        f32x4 r = redR[w][lane], i = redI[w][lane];
        #pragma unroll
        for (int c = 0; c < 4; ++c) { ar[c] += r[c]; ai[c] += i[c]; }
    }

    float vr[4], vi[4];
    if (beta != 0.f) {
        bf16x8 c0 = *(const bf16x8*)&C0C[(size_t)row * 512 + lane * 8];
        #pragma unroll
        for (int c = 0; c < 4; ++c) {
            vr[c] = alpha * ar[c] + beta * (float)c0[2 * c];
            vi[c] = alpha * ai[c] + beta * (float)c0[2 * c + 1];
        }
    } else {
        #pragma unroll
        for (int c = 0; c < 4; ++c) { vr[c] = alpha * ar[c]; vi[c] = alpha * ai[c]; }
    }
    size_t base = (size_t)row * FDIM + lane * 4;
    bf16x4 pr, pi;
    #pragma unroll
    for (int c = 0; c < 4; ++c) { pr[c] = (bf16)vr[c]; pi[c] = (bf16)vi[c]; }
    *(bf16x4*)&Zr[base] = pr;
    *(bf16x4*)&Zi[base] = pi;
    if (ZC) {
        bf16x8 o;
        #pragma unroll
        for (int c = 0; c < 4; ++c) { o[2 * c] = pr[c]; o[2 * c + 1] = pi[c]; }
        *(bf16x8*)&ZC[(size_t)row * 512 + lane * 8] = o;
    }
}

// ---------------------------------------------------------------------------
// 6. wapply via MFMA (R3/R7/R9-validated, byte-identical).
// ---------------------------------------------------------------------------
__global__ __launch_bounds__(256) void wapply_mfma(
    const bf16* __restrict__ Z0r, const bf16* __restrict__ Z0i,
    const bf16* __restrict__ Z1r, const bf16* __restrict__ Z1i,
    const bf16* __restrict__ Z2r, const bf16* __restrict__ Z2i,
    const bf16* __restrict__ Wt,      // [256][768]
    const float* __restrict__ bias,   // [256]
    float* __restrict__ O32r, float* __restrict__ O32i,
    bf16* __restrict__ O16r_r, bf16* __restrict__ O16r_i,
    bf16* __restrict__ OC)
{
    __shared__ __align__(16) bf16 sZr[64 * 32];
    __shared__ __align__(16) bf16 sZi[64 * 32];
    __shared__ __align__(16) bf16 sW [64 * 32];

    const int tid  = threadIdx.x;
    const int wave = tid >> 6;
    const int lane = tid & 63;
    const int rowBase = blockIdx.y * 64;
    const int colBase = blockIdx.x * 64;

    const int srow = lane >> 2;
    const int skc  = (lane & 3) * 8;

    f32x4 accSr[2][2] = {}, accSi[2][2] = {};
    const int wm = wave & 1, wn = wave >> 1;
    const int fr = lane & 15;
    const int fk = (lane >> 4) * 8;

    for (int kb = 0; kb < 3 * FDIM; kb += 32) {
        int order = kb >> 8;
        int kloc  = kb & 255;
        if (wave == 0 || wave == 1) {
            const bf16* z;
            if (wave == 0) z = (order == 0) ? Z0r : (order == 1) ? Z1r : Z2r;
            else           z = (order == 0) ? Z0i : (order == 1) ? Z1i : Z2i;
            bf16* s = (wave == 0) ? sZr : sZi;
            const bf16* g = z + (size_t)(rowBase + srow) * FDIM + kloc + skc;
            #pragma unroll
            for (int t = 0; t < 4; ++t)
                gld_lds16(g + (size_t)t * 16 * FDIM, s + t * 512);
        } else if (wave == 2) {
            const bf16* g = Wt + (size_t)(colBase + srow) * 768 + kb + skc;
            #pragma unroll
            for (int t = 0; t < 4; ++t)
                gld_lds16(g + (size_t)t * 16 * 768, sW + t * 512);
        }
        __syncthreads();

        bf16x8 zr[2], zi[2], wv[2];
        #pragma unroll
        for (int m = 0; m < 2; ++m) {
            int r = wm * 32 + m * 16 + fr;
            zr[m] = *(const bf16x8*)&sZr[r * 32 + fk];
            zi[m] = *(const bf16x8*)&sZi[r * 32 + fk];
        }
        #pragma unroll
        for (int n = 0; n < 2; ++n) {
            int c = wn * 32 + n * 16 + fr;
            wv[n] = *(const bf16x8*)&sW[c * 32 + fk];
        }
        #pragma unroll
        for (int m = 0; m < 2; ++m)
            #pragma unroll
            for (int n = 0; n < 2; ++n) {
                accSr[m][n] = __builtin_amdgcn_mfma_f32_16x16x32_bf16(zr[m], wv[n], accSr[m][n], 0, 0, 0);
                accSi[m][n] = __builtin_amdgcn_mfma_f32_16x16x32_bf16(zi[m], wv[n], accSi[m][n], 0, 0, 0);
            }
        __syncthreads();
    }

    #pragma unroll
    for (int m = 0; m < 2; ++m)
        #pragma unroll
        for (int n = 0; n < 2; ++n) {
            int row0 = rowBase + wm * 32 + m * 16 + (lane >> 4) * 4;
            int col  = colBase + wn * 32 + n * 16 + (lane & 15);
            float bv = bias[col];
            #pragma unroll
            for (int r = 0; r < 4; ++r) {
                float vr = bv - accSi[m][n][r];
                float vi = bv + accSr[m][n][r];
                int row = row0 + r;
                size_t idx = (size_t)row * FDIM + col;
                if (O32r) {
                    O32r[idx] = vr; O32i[idx] = vi;
                }
                if (O16r_r) {
                    O16r_r[idx] = (bf16)vr; O16r_i[idx] = (bf16)vi;
                }
                if (OC) {
                    bf16x2 p; p[0] = (bf16)vr; p[1] = (bf16)vi;
                    ((bf16x2*)OC)[idx] = p;
                }
            }
        }
}

// ---------------------------------------------------------------------------
// 7. Head via MFMA + fused log_softmax (R11-validated: W staged in two
//    guarded passes, idx = tid + e*256 < 384).
// ---------------------------------------------------------------------------
__global__ __launch_bounds__(256) void head_mfma(
    const bf16* __restrict__ Yrb,
    const bf16* __restrict__ Yib,
    const bf16* __restrict__ Wcb,
    const float* __restrict__ bc,
    float* __restrict__ out)          // [4096][40]
{
    __shared__ __align__(16) bf16 sY[64][72];
    __shared__ __align__(16) bf16 sW[48][72];
    __shared__ float sS[64][52];

    const int tid  = threadIdx.x;
    const int wave = tid >> 6;
    const int lane = tid & 63;
    const int r0 = blockIdx.x * 64;

    f32x4 acc[3] = {};

    for (int kb = 0; kb < 512; kb += 64) {
        const bf16* src = (kb < 256) ? Yrb : Yib;
        const int koff = kb & 255;
        #pragma unroll
        for (int e = 0; e < 2; ++e) {
            int idx = tid + e * 256;             // 0..511
            int rr = idx >> 3, kk = (idx & 7) * 8;
            *(bf16x8*)&sY[rr][kk] =
                *(const bf16x8*)&src[(size_t)(r0 + rr) * FDIM + koff + kk];
        }
        #pragma unroll
        for (int e = 0; e < 2; ++e) {
            int idx = tid + e * 256;             // need 0..383
            if (idx < 384) {
                int rr = idx >> 3, kk = (idx & 7) * 8;
                *(bf16x8*)&sW[rr][kk] =
                    *(const bf16x8*)&Wcb[(size_t)rr * 512 + kb + kk];
            }
        }
        __syncthreads();
        #pragma unroll
        for (int ks = 0; ks < 2; ++ks) {
            bf16x8 a = *(const bf16x8*)&sY[wave * 16 + (lane & 15)][ks * 32 + (lane >> 4) * 8];
            #pragma unroll
            for (int n = 0; n < 3; ++n) {
                bf16x8 b = *(const bf16x8*)&sW[n * 16 + (lane & 15)][ks * 32 + (lane >> 4) * 8];
                acc[n] = __builtin_amdgcn_mfma_f32_16x16x32_bf16(a, b, acc[n], 0, 0, 0);
            }
        }
        __syncthreads();
    }

    #pragma unroll
    for (int n = 0; n < 3; ++n) {
        int col = n * 16 + (lane & 15);
        int rloc = wave * 16 + (lane >> 4) * 4;
        #pragma unroll
        for (int r = 0; r < 4; ++r)
            sS[rloc + r][col] = acc[n][r];
    }
    __syncthreads();

    if (tid < 64) {
        float mx = -INFINITY;
        #pragma unroll 8
        for (int c = 0; c < CDIM; ++c) {
            float lv = sS[tid][c] + bc[c];
            sS[tid][c] = lv;
            mx = fmaxf(mx, lv);
        }
        float se = 0.f;
        #pragma unroll 8
        for (int c = 0; c < CDIM; ++c) se += expf(sS[tid][c] - mx);
        float lse = mx + logf(se);
        #pragma unroll 8
        for (int c = 0; c < CDIM; ++c)
            out[(size_t)(r0 + tid) * CDIM + c] = sS[tid][c] - lse;
    }
}

// ---------------------------------------------------------------------------
// Launcher
// ---------------------------------------------------------------------------
extern "C" void kernel_launch(void* const* d_in, const int* in_sizes, int n_in,
                              void* d_out, int out_size, void* d_ws, size_t ws_size,
                              hipStream_t stream) {
    const float* real = (const float*)d_in[0];
    const float* imag = (const float*)d_in[1];
    const int*   edges = (const int*)d_in[2];
    const float* q    = (const float*)d_in[3];
    const float* ew   = (const float*)d_in[4];
    const float* W1   = (const float*)d_in[5];
    const float* b1   = (const float*)d_in[6];
    const float* W2   = (const float*)d_in[7];
    const float* b2   = (const float*)d_in[8];
    const float* Wc   = (const float*)d_in[9];
    const float* bc   = (const float*)d_in[10];
    float* out = (float*)d_out;

    // ---- workspace carve-up ----
    // Zeroed region (single memset, ~8 MB): hkey, hval, cnt, rowsum, colsum.
    char* w = (char*)d_ws;
    int*      hkey   = (int*)w;   w += (size_t)HSIZE * 4;       // 4 MB
    float*    hval   = (float*)w; w += (size_t)HSIZE * 4;       // 4 MB
    int*      cnt    = (int*)w;   w += N_NODES * 4;
    float*    rowsum = (float*)w; w += N_NODES * 4;
    float*    colsum = (float*)w; w += N_NODES * 4;
    size_t zero_bytes = (size_t)((char*)w - (char*)d_ws);
    // Non-zeroed:
    Entry* ent  = (Entry*)w; w += (size_t)N_NODES * CAP * 16;   // 16 MB
    bf16* Xr16 = (bf16*)w; w += NF * 2;
    bf16* Xi16 = (bf16*)w; w += NF * 2;
    bf16* XC   = (bf16*)w; w += NF * 4;                         // interleaved
    bf16* Z1r  = (bf16*)w; w += NF * 2;
    bf16* Z1i  = (bf16*)w; w += NF * 2;
    bf16* Z1C  = (bf16*)w; w += NF * 4;
    bf16* Z2r  = (bf16*)w; w += NF * 2;
    bf16* Z2i  = (bf16*)w; w += NF * 2;
    float* Y1r32 = (float*)w; w += NF * 4;
    float* Y1i32 = (float*)w; w += NF * 4;
    bf16* Y1rb = (bf16*)w; w += NF * 2;
    bf16* Y1ib = (bf16*)w; w += NF * 2;
    bf16* Y1C  = (bf16*)w; w += NF * 4;
    bf16* Y2rb = (bf16*)w; w += NF * 2;
    bf16* Y2ib = (bf16*)w; w += NF * 2;
    bf16* W1t  = (bf16*)w; w += 256 * 768 * 2;
    bf16* W2t  = (bf16*)w; w += 256 * 768 * 2;
    bf16* Wcb  = (bf16*)w; w += 48 * 512 * 2;

    hipMemsetAsync(d_ws, 0, zero_bytes, stream);

    // ---- build sparse L (hash -> ELL) ----
    hash_insert<<<(NEDGE + 255) / 256, 256, 0, stream>>>(edges, ew, hkey, hval,
                                                         rowsum, colsum);
    hash_to_ell<<<HSIZE / 256, 256, 0, stream>>>(hkey, hval, rowsum, colsum,
                                                 q, cnt, ent);

    // ---- casts ----
    cast_in2<<<NF / 256, 256, 0, stream>>>(real, imag, Xr16, Xi16, XC);
    cast_weights<<<(2 * NWT + 48 * 512 + 255) / 256, 256, 0, stream>>>(
        W1, W2, Wc, W1t, W2t, Wcb);

    dim3 gW(FDIM / 64, N_NODES / 64);   // (4, 64)

    // ---- Layer 1 ----
    spmm_k<<<N_NODES, 256, 0, stream>>>(cnt, ent, XC, nullptr,
                                        1.f, 0.f, Z1r, Z1i, Z1C);
    spmm_k<<<N_NODES, 256, 0, stream>>>(cnt, ent, Z1C, XC,
                                        2.f, -1.f, Z2r, Z2i, nullptr);
    wapply_mfma<<<gW, 256, 0, stream>>>(Xr16, Xi16, Z1r, Z1i, Z2r, Z2i,
                                        W1t, b1,
                                        Y1r32, Y1i32,
                                        Y1rb, Y1ib,
                                        Y1C);

    // ---- Layer 2 ----
    spmm_k<<<N_NODES, 256, 0, stream>>>(cnt, ent, Y1C, nullptr,
                                        1.f, 0.f, Z1r, Z1i, Z1C);
    spmm_k<<<N_NODES, 256, 0, stream>>>(cnt, ent, Z1C, Y1C,
                                        2.f, -1.f, Z2r, Z2i, nullptr);
    wapply_mfma<<<gW, 256, 0, stream>>>(Y1rb, Y1ib, Z1r, Z1i, Z2r, Z2i,
                                        W2t, b2,
                                        nullptr, nullptr,
                                        Y2rb, Y2ib,
                                        nullptr);

    // ---- Head ----
    head_mfma<<<64, 256, 0, stream>>>(Y2rb, Y2ib, Wcb, bc, out);
}